// Round 4
// baseline (4237.526 us; speedup 1.0000x reference)
//
#include <hip/hip_runtime.h>

#define NN 50000
#define NE 800000
#define DIN 32
#define DD 96
#define NL 4
#define NCLS 10
#define EPSF 1e-6f
#define EPB 256              // edge budget per block in k_node_edge
#define NBE (NE / EPB + 1)   // 3126 blocks (last catches degree-0 tail nodes)

typedef unsigned short u16;
typedef unsigned int u32;

static __device__ __forceinline__ float bf2f(u16 u) {
    return __uint_as_float(((u32)u) << 16);
}
static __device__ __forceinline__ u16 f2bf(float f) {
    u32 x = __float_as_uint(f);
    x += 0x7FFFu + ((x >> 16) & 1u);   // round-to-nearest-even
    return (u16)(x >> 16);
}

__global__ void k_zero_i(int* __restrict__ p, int n) {
    int i = blockIdx.x * blockDim.x + threadIdx.x;
    if (i < n) p[i] = 0;
}

__global__ void k_hist(const int* __restrict__ dst, int* __restrict__ counts) {
    int i = blockIdx.x * blockDim.x + threadIdx.x;
    if (i < NE) atomicAdd(&counts[dst[i]], 1);
}

// single-block exclusive scan over n counts -> row_ptr[0..n], cursor copy.
__global__ __launch_bounds__(1024) void k_scan(const int* __restrict__ counts,
                                               int* __restrict__ row_ptr,
                                               int* __restrict__ cursor, int n) {
    __shared__ int wsum[16];
    __shared__ int carry_s;
    const int tid = threadIdx.x;
    const int lane = tid & 63, wid = tid >> 6;
    if (tid == 0) carry_s = 0;
    __syncthreads();
    for (int base = 0; base < n; base += 1024) {
        int i = base + tid;
        int v = (i < n) ? counts[i] : 0;
        int x = v;
#pragma unroll
        for (int off = 1; off < 64; off <<= 1) {
            int t = __shfl_up(x, (unsigned)off, 64);
            if (lane >= off) x += t;
        }
        if (lane == 63) wsum[wid] = x;
        __syncthreads();
        if (wid == 0 && lane < 16) {
            int s = wsum[lane];
#pragma unroll
            for (int off = 1; off < 16; off <<= 1) {
                int t = __shfl_up(s, (unsigned)off, 16);
                if (lane >= off) s += t;
            }
            wsum[lane] = s;
        }
        __syncthreads();
        int wbase = (wid > 0) ? wsum[wid - 1] : 0;
        int carry = carry_s;
        int excl = carry + wbase + x - v;
        if (i < n) { row_ptr[i] = excl; cursor[i] = excl; }
        __syncthreads();
        if (tid == 0) carry_s = carry + wsum[15];
        __syncthreads();
    }
    if (tid == 0) row_ptr[n] = carry_s;
}

__global__ void k_scatter(const int* __restrict__ src, const int* __restrict__ dst,
                          int* __restrict__ cursor, int* __restrict__ eperm,
                          int* __restrict__ srcp) {
    int i = blockIdx.x * blockDim.x + threadIdx.x;
    if (i >= NE) return;
    int pos = atomicAdd(&cursor[dst[i]], 1);
    eperm[pos] = i;
    srcp[pos] = src[i];
}

// nstart[b] = first node n with row_ptr[n] >= b*EPB (binary search)
__global__ void k_nstart(const int* __restrict__ row_ptr, int* __restrict__ nstart, int nb) {
    int b = blockIdx.x * blockDim.x + threadIdx.x;
    if (b >= nb) return;
    int target = b * EPB;
    int lo = 0, hi = NN;
    while (lo < hi) {
        int mid = (lo + hi) >> 1;
        if (row_ptr[mid] < target) lo = mid + 1;
        else hi = mid;
    }
    nstart[b] = lo;
}

// node input projection: hbuf[row,j] = h_in[row,:32] @ fp_w + fp_b  (f32 out)
__global__ void k_proj_h(const float* __restrict__ X, const float* __restrict__ W,
                         const float* __restrict__ B, float* __restrict__ Y, long total) {
    long idx = (long)blockIdx.x * blockDim.x + threadIdx.x;
    if (idx >= total) return;
    int row = (int)(idx / DD);
    int j = (int)(idx - (long)row * DD);
    const float* xr = X + (long)row * DIN;
    float acc = B[j];
#pragma unroll
    for (int k = 0; k < DIN; ++k) acc = fmaf(xr[k], W[k * DD + j], acc);
    Y[idx] = acc;
}

// edge input projection into dst-sorted order: ebuf[i] = proj(e_in[eperm[i]]) (bf16)
__global__ void k_proj_e(const float* __restrict__ X, const float* __restrict__ W,
                         const float* __restrict__ B, u16* __restrict__ Y,
                         const int* __restrict__ eperm, long total) {
    long idx = (long)blockIdx.x * blockDim.x + threadIdx.x;
    if (idx >= total) return;
    int row = (int)(idx / DD);
    int j = (int)(idx - (long)row * DD);
    const float* xr = X + (long)eperm[row] * DIN;
    float acc = B[j];
#pragma unroll
    for (int k = 0; k < DIN; ++k) acc = fmaf(xr[k], W[k * DD + j], acc);
    Y[idx] = f2bf(acc);
}

// Fused 4-way node GEMM: from X[nrows,96] compute
//   Y0 = X@W0 + b0 (f32)   Y1..Y3 = bf16(X@Wm + bm)
// X tile staged once; W buffer reused across the 4 matrices.
__global__ __launch_bounds__(192) void k_gemm4(const float* __restrict__ X,
                                               const float* __restrict__ W0, const float* __restrict__ b0,
                                               const float* __restrict__ W1, const float* __restrict__ b1,
                                               const float* __restrict__ W2, const float* __restrict__ b2,
                                               const float* __restrict__ W3, const float* __restrict__ b3,
                                               float* __restrict__ Y0, u16* __restrict__ Y1,
                                               u16* __restrict__ Y2, u16* __restrict__ Y3,
                                               int nrows) {
    __shared__ float ws_w[DD * DD];
    __shared__ float xs[32 * 100];
    const int tid = threadIdx.x;
    const int row0 = blockIdx.x * 32;
#pragma unroll
    for (int t = 0; t < 4; ++t) {
        int q = tid + t * 192;
        int r = q / 24, c4 = q - r * 24;
        int row = row0 + r;
        float4 v = make_float4(0.f, 0.f, 0.f, 0.f);
        if (row < nrows) v = *(const float4*)&X[(long)row * DD + c4 * 4];
        *(float4*)&xs[r * 100 + c4 * 4] = v;
    }
    const float* Ws[4] = {W0, W1, W2, W3};
    const float* Bs[4] = {b0, b1, b2, b3};
    const int je = tid % 24, ge = tid / 24;
    const int j0 = je * 4, r0 = ge * 4;
    for (int m = 0; m < 4; ++m) {
        {
            const float4* Wv = (const float4*)Ws[m];
            float4* wv = (float4*)ws_w;
#pragma unroll
            for (int t = 0; t < 12; ++t) wv[tid + t * 192] = Wv[tid + t * 192];
        }
        __syncthreads();
        float acc[4][4] = {};
#pragma unroll 4
        for (int k4 = 0; k4 < 24; ++k4) {
            const int kk = k4 * 4;
            float4 a0 = *(const float4*)&xs[(r0 + 0) * 100 + kk];
            float4 a1 = *(const float4*)&xs[(r0 + 1) * 100 + kk];
            float4 a2 = *(const float4*)&xs[(r0 + 2) * 100 + kk];
            float4 a3 = *(const float4*)&xs[(r0 + 3) * 100 + kk];
            float4 w0 = *(const float4*)&ws_w[(kk + 0) * DD + j0];
            float4 w1 = *(const float4*)&ws_w[(kk + 1) * DD + j0];
            float4 w2 = *(const float4*)&ws_w[(kk + 2) * DD + j0];
            float4 w3 = *(const float4*)&ws_w[(kk + 3) * DD + j0];
#define ROWFMA(i, a)                                                                  \
    acc[i][0] = fmaf(a.x, w0.x, fmaf(a.y, w1.x, fmaf(a.z, w2.x, fmaf(a.w, w3.x, acc[i][0])))); \
    acc[i][1] = fmaf(a.x, w0.y, fmaf(a.y, w1.y, fmaf(a.z, w2.y, fmaf(a.w, w3.y, acc[i][1])))); \
    acc[i][2] = fmaf(a.x, w0.z, fmaf(a.y, w1.z, fmaf(a.z, w2.z, fmaf(a.w, w3.z, acc[i][2])))); \
    acc[i][3] = fmaf(a.x, w0.w, fmaf(a.y, w1.w, fmaf(a.z, w2.w, fmaf(a.w, w3.w, acc[i][3]))));
            ROWFMA(0, a0) ROWFMA(1, a1) ROWFMA(2, a2) ROWFMA(3, a3)
#undef ROWFMA
        }
        const float* Bm = Bs[m];
        const float bb0 = Bm[j0], bb1 = Bm[j0 + 1], bb2 = Bm[j0 + 2], bb3 = Bm[j0 + 3];
#pragma unroll
        for (int i = 0; i < 4; ++i) {
            int row = row0 + r0 + i;
            if (row >= nrows) continue;
            float v0 = acc[i][0] + bb0, v1 = acc[i][1] + bb1;
            float v2 = acc[i][2] + bb2, v3 = acc[i][3] + bb3;
            if (m == 0) {
                *(float4*)&Y0[(long)row * DD + j0] = make_float4(v0, v1, v2, v3);
            } else {
                u16* Yp = (m == 1) ? Y1 : ((m == 2) ? Y2 : Y3);
                u32 p0 = (u32)f2bf(v0) | ((u32)f2bf(v1) << 16);
                u32 p1 = (u32)f2bf(v2) | ((u32)f2bf(v3) << 16);
                *(uint2*)&Yp[(long)row * DD + j0] = make_uint2(p0, p1);
            }
        }
        __syncthreads();   // ws_w reused next m
    }
}

// Multi-node fused edge+aggregate kernel (edges sorted by dst).
// Block b owns nodes n with row_ptr[n] in [b*EPB,(b+1)*EPB). For each node:
//   e_new = e@Cw + Cb + Dh[srcp] + Eh[n]; sigma = sigmoid(e_new)
//   e += relu(e_new) (in place, bf16); num += Bh[srcp]*sigma; den += sigma
//   h[n] += relu(Ah[n] + num/(den+eps))
__global__ __launch_bounds__(192) void k_node_edge(u16* ebuf,
                                                   const float* __restrict__ Cw,
                                                   const float* __restrict__ Cb,
                                                   const u16* __restrict__ Dh,
                                                   const u16* __restrict__ Eh,
                                                   const u16* __restrict__ Bh,
                                                   const int* __restrict__ srcp,
                                                   const int* __restrict__ row_ptr,
                                                   const int* __restrict__ nstart,
                                                   const float* __restrict__ Ah,
                                                   float* __restrict__ hbuf) {
    __shared__ float cw[DD * DD];     // 36 KB
    __shared__ float xs[16 * 100];    // 6.4 KB
    __shared__ float redn[8][DD];     // 3 KB
    __shared__ float redd[8][DD];     // 3 KB
    __shared__ float sehn[DD];
    __shared__ float scb[DD];
    __shared__ int ssrc[16];
    const int tid = threadIdx.x;
    const int b = blockIdx.x;
    {
        const float4* Wv = (const float4*)Cw;
        float4* wv = (float4*)cw;
#pragma unroll
        for (int t = 0; t < 12; ++t) wv[tid + t * 192] = Wv[tid + t * 192];
    }
    if (tid < DD) scb[tid] = Cb[tid];
    const int je = tid % 24, ge = tid / 24;
    const int j0 = je * 4, rl0 = ge * 2;
    const int lim = (b + 1) * EPB;
    int n = nstart[b];
    __syncthreads();   // cw, scb ready

    while (n < NN) {
        const int r0 = row_ptr[n];
        if (r0 >= lim) break;
        const int r1 = row_ptr[n + 1];
        if (tid < DD) sehn[tid] = bf2f(Eh[(long)n * DD + tid]);
        float s_num[4] = {0.f, 0.f, 0.f, 0.f};
        float s_den[4] = {0.f, 0.f, 0.f, 0.f};

        for (int chunk = r0; chunk < r1; chunk += 16) {
            const int rows = min(16, r1 - chunk);
#pragma unroll
            for (int t = 0; t < 2; ++t) {
                int q = tid + t * 192;
                int r = q / 24, c4 = q - r * 24;
                float* xp = &xs[r * 100 + c4 * 4];
                if (r < rows) {
                    uint2 u = *(const uint2*)&ebuf[(long)(chunk + r) * DD + c4 * 4];
                    xp[0] = bf2f((u16)(u.x & 0xFFFF)); xp[1] = bf2f((u16)(u.x >> 16));
                    xp[2] = bf2f((u16)(u.y & 0xFFFF)); xp[3] = bf2f((u16)(u.y >> 16));
                } else {
                    xp[0] = 0.f; xp[1] = 0.f; xp[2] = 0.f; xp[3] = 0.f;
                }
            }
            if (tid < 16) ssrc[tid] = (chunk + tid < r1) ? srcp[chunk + tid] : 0;
            __syncthreads();
            float acc[2][4] = {};
#pragma unroll 4
            for (int k4 = 0; k4 < 24; ++k4) {
                const int kk = k4 * 4;
                float4 a0 = *(const float4*)&xs[(rl0 + 0) * 100 + kk];
                float4 a1 = *(const float4*)&xs[(rl0 + 1) * 100 + kk];
                float4 w0 = *(const float4*)&cw[(kk + 0) * DD + j0];
                float4 w1 = *(const float4*)&cw[(kk + 1) * DD + j0];
                float4 w2 = *(const float4*)&cw[(kk + 2) * DD + j0];
                float4 w3 = *(const float4*)&cw[(kk + 3) * DD + j0];
#define ROWFMA(i, a)                                                                  \
    acc[i][0] = fmaf(a.x, w0.x, fmaf(a.y, w1.x, fmaf(a.z, w2.x, fmaf(a.w, w3.x, acc[i][0])))); \
    acc[i][1] = fmaf(a.x, w0.y, fmaf(a.y, w1.y, fmaf(a.z, w2.y, fmaf(a.w, w3.y, acc[i][1])))); \
    acc[i][2] = fmaf(a.x, w0.z, fmaf(a.y, w1.z, fmaf(a.z, w2.z, fmaf(a.w, w3.z, acc[i][2])))); \
    acc[i][3] = fmaf(a.x, w0.w, fmaf(a.y, w1.w, fmaf(a.z, w2.w, fmaf(a.w, w3.w, acc[i][3]))));
                ROWFMA(0, a0) ROWFMA(1, a1)
#undef ROWFMA
            }
#pragma unroll
            for (int i = 0; i < 2; ++i) {
                const int rl = rl0 + i;
                if (rl < rows) {
                    const long eg = chunk + rl;
                    const int s = ssrc[rl];
                    const uint2 du = *(const uint2*)&Dh[(long)s * DD + j0];
                    const uint2 bu = *(const uint2*)&Bh[(long)s * DD + j0];
                    float dh0 = bf2f((u16)(du.x & 0xFFFF)), dh1 = bf2f((u16)(du.x >> 16));
                    float dh2 = bf2f((u16)(du.y & 0xFFFF)), dh3 = bf2f((u16)(du.y >> 16));
                    float bh0 = bf2f((u16)(bu.x & 0xFFFF)), bh1 = bf2f((u16)(bu.x >> 16));
                    float bh2 = bf2f((u16)(bu.y & 0xFFFF)), bh3 = bf2f((u16)(bu.y >> 16));
                    float en0 = acc[i][0] + scb[j0 + 0] + dh0 + sehn[j0 + 0];
                    float en1 = acc[i][1] + scb[j0 + 1] + dh1 + sehn[j0 + 1];
                    float en2 = acc[i][2] + scb[j0 + 2] + dh2 + sehn[j0 + 2];
                    float en3 = acc[i][3] + scb[j0 + 3] + dh3 + sehn[j0 + 3];
                    float sg0 = 1.f / (1.f + __expf(-en0));
                    float sg1 = 1.f / (1.f + __expf(-en1));
                    float sg2 = 1.f / (1.f + __expf(-en2));
                    float sg3 = 1.f / (1.f + __expf(-en3));
                    s_num[0] += bh0 * sg0; s_den[0] += sg0;
                    s_num[1] += bh1 * sg1; s_den[1] += sg1;
                    s_num[2] += bh2 * sg2; s_den[2] += sg2;
                    s_num[3] += bh3 * sg3; s_den[3] += sg3;
                    const float* xp = &xs[rl * 100 + j0];
                    float o0 = xp[0] + fmaxf(en0, 0.f), o1 = xp[1] + fmaxf(en1, 0.f);
                    float o2 = xp[2] + fmaxf(en2, 0.f), o3 = xp[3] + fmaxf(en3, 0.f);
                    u32 p0 = (u32)f2bf(o0) | ((u32)f2bf(o1) << 16);
                    u32 p1 = (u32)f2bf(o2) | ((u32)f2bf(o3) << 16);
                    *(uint2*)&ebuf[eg * DD + j0] = make_uint2(p0, p1);
                }
            }
            __syncthreads();   // xs reused next chunk
        }
#pragma unroll
        for (int c = 0; c < 4; ++c) { redn[ge][j0 + c] = s_num[c]; redd[ge][j0 + c] = s_den[c]; }
        __syncthreads();
        if (tid < DD) {
            float num = 0.f, den = 0.f;
#pragma unroll
            for (int g = 0; g < 8; ++g) { num += redn[g][tid]; den += redd[g][tid]; }
            float val = Ah[(long)n * DD + tid] + num / (den + EPSF);
            hbuf[(long)n * DD + tid] += fmaxf(val, 0.f);
        }
        __syncthreads();   // redn/sehn reused next node
        ++n;
    }
}

// small MLP stage, one thread per output element
__global__ void k_mlp(const float* __restrict__ X, const float* __restrict__ W,
                      const float* __restrict__ B, float* __restrict__ Y,
                      int K, int Dout, int act, long total) {
    long idx = (long)blockIdx.x * blockDim.x + threadIdx.x;
    if (idx >= total) return;
    int row = (int)(idx / Dout);
    int j = (int)(idx - (long)row * Dout);
    const float* xr = X + (long)row * K;
    float acc = B[j];
    for (int k = 0; k < K; ++k) acc = fmaf(xr[k], W[k * Dout + j], acc);
    if (act == 1) acc = fmaxf(acc, 0.f);
    else if (act == 2) acc = 1.f / (1.f + __expf(-acc));
    Y[idx] = acc;
}

extern "C" void kernel_launch(void* const* d_in, const int* in_sizes, int n_in,
                              void* d_out, int out_size, void* d_ws, size_t ws_size,
                              hipStream_t stream) {
    const float* h_in = (const float*)d_in[0];
    const float* e_in = (const float*)d_in[1];
    const int* src = (const int*)d_in[2];
    const int* dst = (const int*)d_in[3];
    const float* fp_w = (const float*)d_in[4];
    const float* fp_b = (const float*)d_in[5];
    const float* ep_w = (const float*)d_in[6];
    const float* ep_b = (const float*)d_in[7];
    const float* A_w = (const float*)d_in[8];
    const float* A_b = (const float*)d_in[9];
    const float* B_w = (const float*)d_in[10];
    const float* B_b = (const float*)d_in[11];
    const float* C_w = (const float*)d_in[12];
    const float* C_b = (const float*)d_in[13];
    const float* D_w = (const float*)d_in[14];
    const float* D_b = (const float*)d_in[15];
    const float* E_w = (const float*)d_in[16];
    const float* E_b = (const float*)d_in[17];
    const float* mlp0_w = (const float*)d_in[18];
    const float* mlp0_b = (const float*)d_in[19];
    const float* mlp1_w = (const float*)d_in[20];
    const float* mlp1_b = (const float*)d_in[21];
    const float* mlp2_w = (const float*)d_in[22];
    const float* mlp2_b = (const float*)d_in[23];
    float* out = (float*)d_out;

    const size_t ND = (size_t)NN * DD;
    const size_t ED = (size_t)NE * DD;
    char* w = (char*)d_ws;
    float* hbuf = (float*)w; w += ND * 4;
    float* Ahb  = (float*)w; w += ND * 4;
    u16* Bhb = (u16*)w; w += ND * 2;
    u16* Dhb = (u16*)w; w += ND * 2;
    u16* Ehb = (u16*)w; w += ND * 2;
    u16* ebuf = (u16*)w; w += ED * 2;
    int* counts  = (int*)w; w += (size_t)NN * 4;
    int* row_ptr = (int*)w; w += (size_t)(NN + 1) * 4 + 12;  // keep 16B align after
    int* cursor  = (int*)w; w += (size_t)NN * 4;
    int* eperm   = (int*)w; w += (size_t)NE * 4;
    int* srcp    = (int*)w; w += (size_t)NE * 4;
    int* nstart  = (int*)w; w += (size_t)NBE * 4;
    size_t need = (size_t)(w - (char*)d_ws);
    if (ws_size < need) return;  // uniform -> graph-safe; fails absmax as diagnostic

    // CSR build (dst-sorted edge permutation) + block->node mapping
    k_zero_i<<<(NN + 255) / 256, 256, 0, stream>>>(counts, NN);
    k_hist<<<(NE + 255) / 256, 256, 0, stream>>>(dst, counts);
    k_scan<<<1, 1024, 0, stream>>>(counts, row_ptr, cursor, NN);
    k_scatter<<<(NE + 255) / 256, 256, 0, stream>>>(src, dst, cursor, eperm, srcp);
    k_nstart<<<(NBE + 255) / 256, 256, 0, stream>>>(row_ptr, nstart, NBE);

    // input projections (edge proj lands in dst-sorted order)
    const long totH = (long)ND, totE = (long)ED;
    k_proj_h<<<(int)((totH + 255) / 256), 256, 0, stream>>>(h_in, fp_w, fp_b, hbuf, totH);
    k_proj_e<<<(int)((totE + 255) / 256), 256, 0, stream>>>(e_in, ep_w, ep_b, ebuf, eperm, totE);

    const int gN = (NN + 31) / 32;
    for (int l = 0; l < NL; ++l) {
        const float* Aw = A_w + (size_t)l * DD * DD; const float* Ab = A_b + (size_t)l * DD;
        const float* Bw = B_w + (size_t)l * DD * DD; const float* Bb = B_b + (size_t)l * DD;
        const float* Cw = C_w + (size_t)l * DD * DD; const float* Cb = C_b + (size_t)l * DD;
        const float* Dw = D_w + (size_t)l * DD * DD; const float* Db = D_b + (size_t)l * DD;
        const float* Ew = E_w + (size_t)l * DD * DD; const float* Eb = E_b + (size_t)l * DD;

        k_gemm4<<<gN, 192, 0, stream>>>(hbuf, Aw, Ab, Bw, Bb, Dw, Db, Ew, Eb,
                                        Ahb, Bhb, Dhb, Ehb, NN);
        k_node_edge<<<NBE, 192, 0, stream>>>(ebuf, Cw, Cb, Dhb, Ehb, Bhb, srcp, row_ptr,
                                             nstart, Ahb, hbuf);
    }

    // MLP readout: 96 -> 48 (relu) -> 24 (relu) -> 10 (sigmoid). Reuse Ahb as temps.
    float* y1 = Ahb;                    // [N,48]
    float* y2 = Ahb + (size_t)NN * 48;  // [N,24]
    long t0 = (long)NN * 48, t1 = (long)NN * 24, t2 = (long)NN * NCLS;
    k_mlp<<<(int)((t0 + 255) / 256), 256, 0, stream>>>(hbuf, mlp0_w, mlp0_b, y1, DD, 48, 1, t0);
    k_mlp<<<(int)((t1 + 255) / 256), 256, 0, stream>>>(y1, mlp1_w, mlp1_b, y2, 48, 24, 1, t1);
    k_mlp<<<(int)((t2 + 255) / 256), 256, 0, stream>>>(y2, mlp2_w, mlp2_b, out, 24, NCLS, 2, t2);
}

// Round 5
// 3520.808 us; speedup vs baseline: 1.2036x; 1.2036x over previous
//
#include <hip/hip_runtime.h>

#define NN 50000
#define NE 800000
#define DIN 32
#define DD 96
#define NL 4
#define NCLS 10
#define EPSF 1e-6f

typedef unsigned short u16;
typedef unsigned int u32;

static __device__ __forceinline__ float bf2f(u16 u) {
    return __uint_as_float(((u32)u) << 16);
}
static __device__ __forceinline__ u16 f2bf(float f) {
    u32 x = __float_as_uint(f);
    x += 0x7FFFu + ((x >> 16) & 1u);   // round-to-nearest-even
    return (u16)(x >> 16);
}
// pack two f32 -> u32 of two bf16 (lo = a, hi = b)
static __device__ __forceinline__ u32 pk2(float a, float b) {
    return (u32)f2bf(a) | ((u32)f2bf(b) << 16);
}
// unpack u32 (two bf16) -> two f32
static __device__ __forceinline__ float unlo(u32 u) { return __uint_as_float(u << 16); }
static __device__ __forceinline__ float unhi(u32 u) { return __uint_as_float(u & 0xFFFF0000u); }

__global__ void k_zero_i(int* __restrict__ p, int n) {
    int i = blockIdx.x * blockDim.x + threadIdx.x;
    if (i < n) p[i] = 0;
}

__global__ void k_hist(const int* __restrict__ dst, int* __restrict__ counts) {
    int i = blockIdx.x * blockDim.x + threadIdx.x;
    if (i < NE) atomicAdd(&counts[dst[i]], 1);
}

// single-block exclusive scan over n counts -> row_ptr[0..n], cursor copy.
__global__ __launch_bounds__(1024) void k_scan(const int* __restrict__ counts,
                                               int* __restrict__ row_ptr,
                                               int* __restrict__ cursor, int n) {
    __shared__ int wsum[16];
    __shared__ int carry_s;
    const int tid = threadIdx.x;
    const int lane = tid & 63, wid = tid >> 6;
    if (tid == 0) carry_s = 0;
    __syncthreads();
    for (int base = 0; base < n; base += 1024) {
        int i = base + tid;
        int v = (i < n) ? counts[i] : 0;
        int x = v;
#pragma unroll
        for (int off = 1; off < 64; off <<= 1) {
            int t = __shfl_up(x, (unsigned)off, 64);
            if (lane >= off) x += t;
        }
        if (lane == 63) wsum[wid] = x;
        __syncthreads();
        if (wid == 0 && lane < 16) {
            int s = wsum[lane];
#pragma unroll
            for (int off = 1; off < 16; off <<= 1) {
                int t = __shfl_up(s, (unsigned)off, 16);
                if (lane >= off) s += t;
            }
            wsum[lane] = s;
        }
        __syncthreads();
        int wbase = (wid > 0) ? wsum[wid - 1] : 0;
        int carry = carry_s;
        int excl = carry + wbase + x - v;
        if (i < n) { row_ptr[i] = excl; cursor[i] = excl; }
        __syncthreads();
        if (tid == 0) carry_s = carry + wsum[15];
        __syncthreads();
    }
    if (tid == 0) row_ptr[n] = carry_s;
}

__global__ void k_scatter(const int* __restrict__ src, const int* __restrict__ dst,
                          int* __restrict__ cursor, int* __restrict__ eperm,
                          int* __restrict__ srcp) {
    int i = blockIdx.x * blockDim.x + threadIdx.x;
    if (i >= NE) return;
    int pos = atomicAdd(&cursor[dst[i]], 1);
    eperm[pos] = i;
    srcp[pos] = src[i];
}

// node input projection: hbuf[row,j] = h_in[row,:32] @ fp_w + fp_b  (f32 out)
__global__ void k_proj_h(const float* __restrict__ X, const float* __restrict__ W,
                         const float* __restrict__ B, float* __restrict__ Y, long total) {
    long idx = (long)blockIdx.x * blockDim.x + threadIdx.x;
    if (idx >= total) return;
    int row = (int)(idx / DD);
    int j = (int)(idx - (long)row * DD);
    const float* xr = X + (long)row * DIN;
    float acc = B[j];
#pragma unroll
    for (int k = 0; k < DIN; ++k) acc = fmaf(xr[k], W[k * DD + j], acc);
    Y[idx] = acc;
}

// edge input projection into dst-sorted order: ebuf[i] = proj(e_in[eperm[i]]) (bf16)
__global__ void k_proj_e(const float* __restrict__ X, const float* __restrict__ W,
                         const float* __restrict__ B, u16* __restrict__ Y,
                         const int* __restrict__ eperm, long total) {
    long idx = (long)blockIdx.x * blockDim.x + threadIdx.x;
    if (idx >= total) return;
    int row = (int)(idx / DD);
    int j = (int)(idx - (long)row * DD);
    const float* xr = X + (long)eperm[row] * DIN;
    float acc = B[j];
#pragma unroll
    for (int k = 0; k < DIN; ++k) acc = fmaf(xr[k], W[k * DD + j], acc);
    Y[idx] = f2bf(acc);
}

// Fused 4-way node GEMM: from X[nrows,96] compute
//   Y0 = X@W0 + b0 (f32)   Y1..Y3 = bf16(X@Wm + bm)
// X tile staged once (f32); W staged per-matrix as packed bf16 (18 KB).
__global__ __launch_bounds__(192) void k_gemm4(const float* __restrict__ X,
                                               const float* __restrict__ W0, const float* __restrict__ b0,
                                               const float* __restrict__ W1, const float* __restrict__ b1,
                                               const float* __restrict__ W2, const float* __restrict__ b2,
                                               const float* __restrict__ W3, const float* __restrict__ b3,
                                               float* __restrict__ Y0, u16* __restrict__ Y1,
                                               u16* __restrict__ Y2, u16* __restrict__ Y3,
                                               int nrows) {
    __shared__ u32 wsp[DD * 48];       // 18 KB bf16-packed W [k][j/2]
    __shared__ float xs[32 * 100];     // 12.8 KB
    const int tid = threadIdx.x;
    const int row0 = blockIdx.x * 32;
#pragma unroll
    for (int t = 0; t < 4; ++t) {
        int q = tid + t * 192;
        int r = q / 24, c4 = q - r * 24;
        int row = row0 + r;
        float4 v = make_float4(0.f, 0.f, 0.f, 0.f);
        if (row < nrows) v = *(const float4*)&X[(long)row * DD + c4 * 4];
        *(float4*)&xs[r * 100 + c4 * 4] = v;
    }
    const float* Ws[4] = {W0, W1, W2, W3};
    const float* Bs[4] = {b0, b1, b2, b3};
    const int je = tid % 24, ge = tid / 24;
    const int j0 = je * 4, r0 = ge * 4;
    for (int m = 0; m < 4; ++m) {
        {
            const float4* Wv = (const float4*)Ws[m];
            uint2* wv = (uint2*)wsp;
#pragma unroll
            for (int t = 0; t < 12; ++t) {
                float4 v = Wv[tid + t * 192];
                wv[tid + t * 192] = make_uint2(pk2(v.x, v.y), pk2(v.z, v.w));
            }
        }
        __syncthreads();
        float acc[4][4] = {};
#pragma unroll 4
        for (int k4 = 0; k4 < 24; ++k4) {
            const int kk = k4 * 4;
            float4 a0 = *(const float4*)&xs[(r0 + 0) * 100 + kk];
            float4 a1 = *(const float4*)&xs[(r0 + 1) * 100 + kk];
            float4 a2 = *(const float4*)&xs[(r0 + 2) * 100 + kk];
            float4 a3 = *(const float4*)&xs[(r0 + 3) * 100 + kk];
            uint2 u0 = *(const uint2*)&wsp[(kk + 0) * 48 + je * 2];
            uint2 u1 = *(const uint2*)&wsp[(kk + 1) * 48 + je * 2];
            uint2 u2 = *(const uint2*)&wsp[(kk + 2) * 48 + je * 2];
            uint2 u3 = *(const uint2*)&wsp[(kk + 3) * 48 + je * 2];
            float4 w0 = make_float4(unlo(u0.x), unhi(u0.x), unlo(u0.y), unhi(u0.y));
            float4 w1 = make_float4(unlo(u1.x), unhi(u1.x), unlo(u1.y), unhi(u1.y));
            float4 w2 = make_float4(unlo(u2.x), unhi(u2.x), unlo(u2.y), unhi(u2.y));
            float4 w3 = make_float4(unlo(u3.x), unhi(u3.x), unlo(u3.y), unhi(u3.y));
#define ROWFMA(i, a)                                                                  \
    acc[i][0] = fmaf(a.x, w0.x, fmaf(a.y, w1.x, fmaf(a.z, w2.x, fmaf(a.w, w3.x, acc[i][0])))); \
    acc[i][1] = fmaf(a.x, w0.y, fmaf(a.y, w1.y, fmaf(a.z, w2.y, fmaf(a.w, w3.y, acc[i][1])))); \
    acc[i][2] = fmaf(a.x, w0.z, fmaf(a.y, w1.z, fmaf(a.z, w2.z, fmaf(a.w, w3.z, acc[i][2])))); \
    acc[i][3] = fmaf(a.x, w0.w, fmaf(a.y, w1.w, fmaf(a.z, w2.w, fmaf(a.w, w3.w, acc[i][3]))));
            ROWFMA(0, a0) ROWFMA(1, a1) ROWFMA(2, a2) ROWFMA(3, a3)
#undef ROWFMA
        }
        const float* Bm = Bs[m];
        const float bb0 = Bm[j0], bb1 = Bm[j0 + 1], bb2 = Bm[j0 + 2], bb3 = Bm[j0 + 3];
#pragma unroll
        for (int i = 0; i < 4; ++i) {
            int row = row0 + r0 + i;
            if (row >= nrows) continue;
            float v0 = acc[i][0] + bb0, v1 = acc[i][1] + bb1;
            float v2 = acc[i][2] + bb2, v3 = acc[i][3] + bb3;
            if (m == 0) {
                *(float4*)&Y0[(long)row * DD + j0] = make_float4(v0, v1, v2, v3);
            } else {
                u16* Yp = (m == 1) ? Y1 : ((m == 2) ? Y2 : Y3);
                *(uint2*)&Yp[(long)row * DD + j0] = make_uint2(pk2(v0, v1), pk2(v2, v3));
            }
        }
        __syncthreads();   // wsp reused next m
    }
}

// Per-destination-node fused edge+aggregate kernel (edges sorted by dst).
// Cw staged as packed bf16 (18 KB) -> ~31.5 KB LDS -> 5 blocks/CU.
__global__ __launch_bounds__(192) void k_node_edge(u16* ebuf,
                                                   const float* __restrict__ Cw,
                                                   const float* __restrict__ Cb,
                                                   const u16* __restrict__ Dh,
                                                   const u16* __restrict__ Eh,
                                                   const u16* __restrict__ Bh,
                                                   const int* __restrict__ srcp,
                                                   const int* __restrict__ row_ptr,
                                                   const float* __restrict__ Ah,
                                                   float* __restrict__ hbuf) {
    __shared__ u32 cwp[DD * 48];      // 18 KB bf16-packed Cw
    __shared__ float xs[16 * 100];    // 6.4 KB
    __shared__ float redn[8][DD];     // 3 KB
    __shared__ float redd[8][DD];     // 3 KB
    __shared__ float sehn[DD];
    __shared__ float scb[DD];
    __shared__ int ssrc[16];
    const int tid = threadIdx.x;
    const int n = blockIdx.x;
    const int r0 = row_ptr[n], r1 = row_ptr[n + 1];
    {
        const float4* Wv = (const float4*)Cw;
        uint2* wv = (uint2*)cwp;
#pragma unroll
        for (int t = 0; t < 12; ++t) {
            float4 v = Wv[tid + t * 192];
            wv[tid + t * 192] = make_uint2(pk2(v.x, v.y), pk2(v.z, v.w));
        }
    }
    if (tid < DD) sehn[tid] = bf2f(Eh[(long)n * DD + tid]);
    else if (tid < 2 * DD) scb[tid - DD] = Cb[tid - DD];
    const int je = tid % 24, ge = tid / 24;
    const int j0 = je * 4, rl0 = ge * 2;
    float s_num[4] = {0.f, 0.f, 0.f, 0.f};
    float s_den[4] = {0.f, 0.f, 0.f, 0.f};
    __syncthreads();

    for (int chunk = r0; chunk < r1; chunk += 16) {
        const int rows = min(16, r1 - chunk);
#pragma unroll
        for (int t = 0; t < 2; ++t) {
            int q = tid + t * 192;
            int r = q / 24, c4 = q - r * 24;
            float* xp = &xs[r * 100 + c4 * 4];
            if (r < rows) {
                uint2 u = *(const uint2*)&ebuf[(long)(chunk + r) * DD + c4 * 4];
                xp[0] = unlo(u.x); xp[1] = unhi(u.x);
                xp[2] = unlo(u.y); xp[3] = unhi(u.y);
            } else {
                xp[0] = 0.f; xp[1] = 0.f; xp[2] = 0.f; xp[3] = 0.f;
            }
        }
        if (tid < 16) ssrc[tid] = (chunk + tid < r1) ? srcp[chunk + tid] : 0;
        __syncthreads();
        float acc[2][4] = {};
#pragma unroll 4
        for (int k4 = 0; k4 < 24; ++k4) {
            const int kk = k4 * 4;
            float4 a0 = *(const float4*)&xs[(rl0 + 0) * 100 + kk];
            float4 a1 = *(const float4*)&xs[(rl0 + 1) * 100 + kk];
            uint2 u0 = *(const uint2*)&cwp[(kk + 0) * 48 + je * 2];
            uint2 u1 = *(const uint2*)&cwp[(kk + 1) * 48 + je * 2];
            uint2 u2 = *(const uint2*)&cwp[(kk + 2) * 48 + je * 2];
            uint2 u3 = *(const uint2*)&cwp[(kk + 3) * 48 + je * 2];
            float4 w0 = make_float4(unlo(u0.x), unhi(u0.x), unlo(u0.y), unhi(u0.y));
            float4 w1 = make_float4(unlo(u1.x), unhi(u1.x), unlo(u1.y), unhi(u1.y));
            float4 w2 = make_float4(unlo(u2.x), unhi(u2.x), unlo(u2.y), unhi(u2.y));
            float4 w3 = make_float4(unlo(u3.x), unhi(u3.x), unlo(u3.y), unhi(u3.y));
#define ROWFMA(i, a)                                                                  \
    acc[i][0] = fmaf(a.x, w0.x, fmaf(a.y, w1.x, fmaf(a.z, w2.x, fmaf(a.w, w3.x, acc[i][0])))); \
    acc[i][1] = fmaf(a.x, w0.y, fmaf(a.y, w1.y, fmaf(a.z, w2.y, fmaf(a.w, w3.y, acc[i][1])))); \
    acc[i][2] = fmaf(a.x, w0.z, fmaf(a.y, w1.z, fmaf(a.z, w2.z, fmaf(a.w, w3.z, acc[i][2])))); \
    acc[i][3] = fmaf(a.x, w0.w, fmaf(a.y, w1.w, fmaf(a.z, w2.w, fmaf(a.w, w3.w, acc[i][3]))));
            ROWFMA(0, a0) ROWFMA(1, a1)
#undef ROWFMA
        }
#pragma unroll
        for (int i = 0; i < 2; ++i) {
            const int rl = rl0 + i;
            if (rl < rows) {
                const long eg = chunk + rl;
                const int s = ssrc[rl];
                const uint2 du = *(const uint2*)&Dh[(long)s * DD + j0];
                const uint2 bu = *(const uint2*)&Bh[(long)s * DD + j0];
                float en0 = acc[i][0] + scb[j0 + 0] + unlo(du.x) + sehn[j0 + 0];
                float en1 = acc[i][1] + scb[j0 + 1] + unhi(du.x) + sehn[j0 + 1];
                float en2 = acc[i][2] + scb[j0 + 2] + unlo(du.y) + sehn[j0 + 2];
                float en3 = acc[i][3] + scb[j0 + 3] + unhi(du.y) + sehn[j0 + 3];
                float sg0 = 1.f / (1.f + __expf(-en0));
                float sg1 = 1.f / (1.f + __expf(-en1));
                float sg2 = 1.f / (1.f + __expf(-en2));
                float sg3 = 1.f / (1.f + __expf(-en3));
                s_num[0] += unlo(bu.x) * sg0; s_den[0] += sg0;
                s_num[1] += unhi(bu.x) * sg1; s_den[1] += sg1;
                s_num[2] += unlo(bu.y) * sg2; s_den[2] += sg2;
                s_num[3] += unhi(bu.y) * sg3; s_den[3] += sg3;
                const float* xp = &xs[rl * 100 + j0];
                float o0 = xp[0] + fmaxf(en0, 0.f), o1 = xp[1] + fmaxf(en1, 0.f);
                float o2 = xp[2] + fmaxf(en2, 0.f), o3 = xp[3] + fmaxf(en3, 0.f);
                *(uint2*)&ebuf[eg * DD + j0] = make_uint2(pk2(o0, o1), pk2(o2, o3));
            }
        }
        __syncthreads();   // xs reused next chunk
    }
#pragma unroll
    for (int c = 0; c < 4; ++c) { redn[ge][j0 + c] = s_num[c]; redd[ge][j0 + c] = s_den[c]; }
    __syncthreads();
    if (tid < DD) {
        float num = 0.f, den = 0.f;
#pragma unroll
        for (int g = 0; g < 8; ++g) { num += redn[g][tid]; den += redd[g][tid]; }
        float val = Ah[(long)n * DD + tid] + num / (den + EPSF);
        hbuf[(long)n * DD + tid] += fmaxf(val, 0.f);
    }
}

// small MLP stage, one thread per output element
__global__ void k_mlp(const float* __restrict__ X, const float* __restrict__ W,
                      const float* __restrict__ B, float* __restrict__ Y,
                      int K, int Dout, int act, long total) {
    long idx = (long)blockIdx.x * blockDim.x + threadIdx.x;
    if (idx >= total) return;
    int row = (int)(idx / Dout);
    int j = (int)(idx - (long)row * Dout);
    const float* xr = X + (long)row * K;
    float acc = B[j];
    for (int k = 0; k < K; ++k) acc = fmaf(xr[k], W[k * Dout + j], acc);
    if (act == 1) acc = fmaxf(acc, 0.f);
    else if (act == 2) acc = 1.f / (1.f + __expf(-acc));
    Y[idx] = acc;
}

extern "C" void kernel_launch(void* const* d_in, const int* in_sizes, int n_in,
                              void* d_out, int out_size, void* d_ws, size_t ws_size,
                              hipStream_t stream) {
    const float* h_in = (const float*)d_in[0];
    const float* e_in = (const float*)d_in[1];
    const int* src = (const int*)d_in[2];
    const int* dst = (const int*)d_in[3];
    const float* fp_w = (const float*)d_in[4];
    const float* fp_b = (const float*)d_in[5];
    const float* ep_w = (const float*)d_in[6];
    const float* ep_b = (const float*)d_in[7];
    const float* A_w = (const float*)d_in[8];
    const float* A_b = (const float*)d_in[9];
    const float* B_w = (const float*)d_in[10];
    const float* B_b = (const float*)d_in[11];
    const float* C_w = (const float*)d_in[12];
    const float* C_b = (const float*)d_in[13];
    const float* D_w = (const float*)d_in[14];
    const float* D_b = (const float*)d_in[15];
    const float* E_w = (const float*)d_in[16];
    const float* E_b = (const float*)d_in[17];
    const float* mlp0_w = (const float*)d_in[18];
    const float* mlp0_b = (const float*)d_in[19];
    const float* mlp1_w = (const float*)d_in[20];
    const float* mlp1_b = (const float*)d_in[21];
    const float* mlp2_w = (const float*)d_in[22];
    const float* mlp2_b = (const float*)d_in[23];
    float* out = (float*)d_out;

    const size_t ND = (size_t)NN * DD;
    const size_t ED = (size_t)NE * DD;
    char* w = (char*)d_ws;
    float* hbuf = (float*)w; w += ND * 4;
    float* Ahb  = (float*)w; w += ND * 4;
    u16* Bhb = (u16*)w; w += ND * 2;
    u16* Dhb = (u16*)w; w += ND * 2;
    u16* Ehb = (u16*)w; w += ND * 2;
    u16* ebuf = (u16*)w; w += ED * 2;
    int* counts  = (int*)w; w += (size_t)NN * 4;
    int* row_ptr = (int*)w; w += (size_t)(NN + 1) * 4 + 12;  // keep 16B align after
    int* cursor  = (int*)w; w += (size_t)NN * 4;
    int* eperm   = (int*)w; w += (size_t)NE * 4;
    int* srcp    = (int*)w; w += (size_t)NE * 4;
    size_t need = (size_t)(w - (char*)d_ws);
    if (ws_size < need) return;  // uniform -> graph-safe; fails absmax as diagnostic

    // CSR build (dst-sorted edge permutation)
    k_zero_i<<<(NN + 255) / 256, 256, 0, stream>>>(counts, NN);
    k_hist<<<(NE + 255) / 256, 256, 0, stream>>>(dst, counts);
    k_scan<<<1, 1024, 0, stream>>>(counts, row_ptr, cursor, NN);
    k_scatter<<<(NE + 255) / 256, 256, 0, stream>>>(src, dst, cursor, eperm, srcp);

    // input projections (edge proj lands in dst-sorted order)
    const long totH = (long)ND, totE = (long)ED;
    k_proj_h<<<(int)((totH + 255) / 256), 256, 0, stream>>>(h_in, fp_w, fp_b, hbuf, totH);
    k_proj_e<<<(int)((totE + 255) / 256), 256, 0, stream>>>(e_in, ep_w, ep_b, ebuf, eperm, totE);

    const int gN = (NN + 31) / 32;
    for (int l = 0; l < NL; ++l) {
        const float* Aw = A_w + (size_t)l * DD * DD; const float* Ab = A_b + (size_t)l * DD;
        const float* Bw = B_w + (size_t)l * DD * DD; const float* Bb = B_b + (size_t)l * DD;
        const float* Cw = C_w + (size_t)l * DD * DD; const float* Cb = C_b + (size_t)l * DD;
        const float* Dw = D_w + (size_t)l * DD * DD; const float* Db = D_b + (size_t)l * DD;
        const float* Ew = E_w + (size_t)l * DD * DD; const float* Eb = E_b + (size_t)l * DD;

        k_gemm4<<<gN, 192, 0, stream>>>(hbuf, Aw, Ab, Bw, Bb, Dw, Db, Ew, Eb,
                                        Ahb, Bhb, Dhb, Ehb, NN);
        k_node_edge<<<NN, 192, 0, stream>>>(ebuf, Cw, Cb, Dhb, Ehb, Bhb, srcp, row_ptr,
                                            Ahb, hbuf);
    }

    // MLP readout: 96 -> 48 (relu) -> 24 (relu) -> 10 (sigmoid). Reuse Ahb as temps.
    float* y1 = Ahb;                    // [N,48]
    float* y2 = Ahb + (size_t)NN * 48;  // [N,24]
    long t0 = (long)NN * 48, t1 = (long)NN * 24, t2 = (long)NN * NCLS;
    k_mlp<<<(int)((t0 + 255) / 256), 256, 0, stream>>>(hbuf, mlp0_w, mlp0_b, y1, DD, 48, 1, t0);
    k_mlp<<<(int)((t1 + 255) / 256), 256, 0, stream>>>(y1, mlp1_w, mlp1_b, y2, 48, 24, 1, t1);
    k_mlp<<<(int)((t2 + 255) / 256), 256, 0, stream>>>(y2, mlp2_w, mlp2_b, out, 24, NCLS, 2, t2);
}

// Round 6
// 3232.529 us; speedup vs baseline: 1.3109x; 1.0892x over previous
//
#include <hip/hip_runtime.h>

#define NN 50000
#define NE 800000
#define DIN 32
#define DD 96
#define NL 4
#define NCLS 10
#define EPSF 1e-6f

typedef unsigned short u16;
typedef unsigned int u32;

static __device__ __forceinline__ float bf2f(u16 u) {
    return __uint_as_float(((u32)u) << 16);
}
static __device__ __forceinline__ u16 f2bf(float f) {
    u32 x = __float_as_uint(f);
    x += 0x7FFFu + ((x >> 16) & 1u);   // round-to-nearest-even
    return (u16)(x >> 16);
}
// pack two f32 -> u32 of two bf16 (lo = a, hi = b)
static __device__ __forceinline__ u32 pk2(float a, float b) {
    return (u32)f2bf(a) | ((u32)f2bf(b) << 16);
}
// unpack u32 (two bf16) -> two f32
static __device__ __forceinline__ float unlo(u32 u) { return __uint_as_float(u << 16); }
static __device__ __forceinline__ float unhi(u32 u) { return __uint_as_float(u & 0xFFFF0000u); }

__global__ void k_zero_i(int* __restrict__ p, int n) {
    int i = blockIdx.x * blockDim.x + threadIdx.x;
    if (i < n) p[i] = 0;
}

__global__ void k_hist(const int* __restrict__ dst, int* __restrict__ counts) {
    int i = blockIdx.x * blockDim.x + threadIdx.x;
    if (i < NE) atomicAdd(&counts[dst[i]], 1);
}

// single-block exclusive scan over n counts -> row_ptr[0..n], cursor copy.
__global__ __launch_bounds__(1024) void k_scan(const int* __restrict__ counts,
                                               int* __restrict__ row_ptr,
                                               int* __restrict__ cursor, int n) {
    __shared__ int wsum[16];
    __shared__ int carry_s;
    const int tid = threadIdx.x;
    const int lane = tid & 63, wid = tid >> 6;
    if (tid == 0) carry_s = 0;
    __syncthreads();
    for (int base = 0; base < n; base += 1024) {
        int i = base + tid;
        int v = (i < n) ? counts[i] : 0;
        int x = v;
#pragma unroll
        for (int off = 1; off < 64; off <<= 1) {
            int t = __shfl_up(x, (unsigned)off, 64);
            if (lane >= off) x += t;
        }
        if (lane == 63) wsum[wid] = x;
        __syncthreads();
        if (wid == 0 && lane < 16) {
            int s = wsum[lane];
#pragma unroll
            for (int off = 1; off < 16; off <<= 1) {
                int t = __shfl_up(s, (unsigned)off, 16);
                if (lane >= off) s += t;
            }
            wsum[lane] = s;
        }
        __syncthreads();
        int wbase = (wid > 0) ? wsum[wid - 1] : 0;
        int carry = carry_s;
        int excl = carry + wbase + x - v;
        if (i < n) { row_ptr[i] = excl; cursor[i] = excl; }
        __syncthreads();
        if (tid == 0) carry_s = carry + wsum[15];
        __syncthreads();
    }
    if (tid == 0) row_ptr[n] = carry_s;
}

__global__ void k_scatter(const int* __restrict__ src, const int* __restrict__ dst,
                          int* __restrict__ cursor, int* __restrict__ eperm,
                          int* __restrict__ srcp) {
    int i = blockIdx.x * blockDim.x + threadIdx.x;
    if (i >= NE) return;
    int pos = atomicAdd(&cursor[dst[i]], 1);
    eperm[pos] = i;
    srcp[pos] = src[i];
}

// Tiled input projection: Y[row,:] = X[permrow,:DIN] @ W[DIN,DD] + B
// 32 rows/block, W (12 KB) + X tile (4.2 KB padded) in LDS, 4x4 micro-tile.
// PERM: gather source row via eperm. BFOUT: bf16-packed output.
template <bool BFOUT, bool PERM>
__global__ __launch_bounds__(192) void k_proj_t(const float* __restrict__ X,
                                                const float* __restrict__ W,
                                                const float* __restrict__ B,
                                                void* __restrict__ Y,
                                                const int* __restrict__ eperm,
                                                int nrows) {
    __shared__ float ws_w[DIN * DD];   // 12 KB, [k][j]
    __shared__ float xs[32][DIN + 1];  // 4.2 KB, pad -> bank spread
    const int tid = threadIdx.x;
    const int row0 = blockIdx.x * 32;
    {   // stage W: 768 float4
        const float4* Wv = (const float4*)W;
        float4* wv = (float4*)ws_w;
#pragma unroll
        for (int t = 0; t < 4; ++t) wv[tid + t * 192] = Wv[tid + t * 192];
    }
    {   // stage X: 32 rows x 8 float4 = 256 float4
#pragma unroll
        for (int t = 0; t < 2; ++t) {
            int q = tid + t * 192;
            if (q < 256) {
                int r = q >> 3, c4 = q & 7;
                int grow = row0 + r;
                float4 v = make_float4(0.f, 0.f, 0.f, 0.f);
                if (grow < nrows) {
                    long srow = PERM ? (long)eperm[grow] : (long)grow;
                    v = *(const float4*)&X[srow * DIN + c4 * 4];
                }
                xs[r][c4 * 4 + 0] = v.x; xs[r][c4 * 4 + 1] = v.y;
                xs[r][c4 * 4 + 2] = v.z; xs[r][c4 * 4 + 3] = v.w;
            }
        }
    }
    __syncthreads();
    const int je = tid % 24, ge = tid / 24;   // 24 col-groups x 8 row-groups
    const int j0 = je * 4, r0 = ge * 4;
    float acc[4][4] = {};
#pragma unroll
    for (int kk = 0; kk < DIN; kk += 4) {
        float4 w0 = *(const float4*)&ws_w[(kk + 0) * DD + j0];
        float4 w1 = *(const float4*)&ws_w[(kk + 1) * DD + j0];
        float4 w2 = *(const float4*)&ws_w[(kk + 2) * DD + j0];
        float4 w3 = *(const float4*)&ws_w[(kk + 3) * DD + j0];
#pragma unroll
        for (int i = 0; i < 4; ++i) {
            const float a0 = xs[r0 + i][kk + 0], a1 = xs[r0 + i][kk + 1];
            const float a2 = xs[r0 + i][kk + 2], a3 = xs[r0 + i][kk + 3];
            acc[i][0] = fmaf(a0, w0.x, fmaf(a1, w1.x, fmaf(a2, w2.x, fmaf(a3, w3.x, acc[i][0]))));
            acc[i][1] = fmaf(a0, w0.y, fmaf(a1, w1.y, fmaf(a2, w2.y, fmaf(a3, w3.y, acc[i][1]))));
            acc[i][2] = fmaf(a0, w0.z, fmaf(a1, w1.z, fmaf(a2, w2.z, fmaf(a3, w3.z, acc[i][2]))));
            acc[i][3] = fmaf(a0, w0.w, fmaf(a1, w1.w, fmaf(a2, w2.w, fmaf(a3, w3.w, acc[i][3]))));
        }
    }
    const float b0 = B[j0], b1 = B[j0 + 1], b2 = B[j0 + 2], b3 = B[j0 + 3];
#pragma unroll
    for (int i = 0; i < 4; ++i) {
        int row = row0 + r0 + i;
        if (row >= nrows) continue;
        float v0 = acc[i][0] + b0, v1 = acc[i][1] + b1;
        float v2 = acc[i][2] + b2, v3 = acc[i][3] + b3;
        if (BFOUT) {
            *(uint2*)((u16*)Y + (long)row * DD + j0) = make_uint2(pk2(v0, v1), pk2(v2, v3));
        } else {
            *(float4*)((float*)Y + (long)row * DD + j0) = make_float4(v0, v1, v2, v3);
        }
    }
}

// Fused 4-way node GEMM: from X[nrows,96] compute
//   Y0 = X@W0 + b0 (f32)   Y1..Y3 = bf16(X@Wm + bm)
// X tile staged once (f32); W staged per-matrix as packed bf16 (18 KB).
__global__ __launch_bounds__(192) void k_gemm4(const float* __restrict__ X,
                                               const float* __restrict__ W0, const float* __restrict__ b0,
                                               const float* __restrict__ W1, const float* __restrict__ b1,
                                               const float* __restrict__ W2, const float* __restrict__ b2,
                                               const float* __restrict__ W3, const float* __restrict__ b3,
                                               float* __restrict__ Y0, u16* __restrict__ Y1,
                                               u16* __restrict__ Y2, u16* __restrict__ Y3,
                                               int nrows) {
    __shared__ u32 wsp[DD * 48];       // 18 KB bf16-packed W [k][j/2]
    __shared__ float xs[32 * 100];     // 12.8 KB
    const int tid = threadIdx.x;
    const int row0 = blockIdx.x * 32;
#pragma unroll
    for (int t = 0; t < 4; ++t) {
        int q = tid + t * 192;
        int r = q / 24, c4 = q - r * 24;
        int row = row0 + r;
        float4 v = make_float4(0.f, 0.f, 0.f, 0.f);
        if (row < nrows) v = *(const float4*)&X[(long)row * DD + c4 * 4];
        *(float4*)&xs[r * 100 + c4 * 4] = v;
    }
    const float* Ws[4] = {W0, W1, W2, W3};
    const float* Bs[4] = {b0, b1, b2, b3};
    const int je = tid % 24, ge = tid / 24;
    const int j0 = je * 4, r0 = ge * 4;
    for (int m = 0; m < 4; ++m) {
        {
            const float4* Wv = (const float4*)Ws[m];
            uint2* wv = (uint2*)wsp;
#pragma unroll
            for (int t = 0; t < 12; ++t) {
                float4 v = Wv[tid + t * 192];
                wv[tid + t * 192] = make_uint2(pk2(v.x, v.y), pk2(v.z, v.w));
            }
        }
        __syncthreads();
        float acc[4][4] = {};
#pragma unroll 4
        for (int k4 = 0; k4 < 24; ++k4) {
            const int kk = k4 * 4;
            float4 a0 = *(const float4*)&xs[(r0 + 0) * 100 + kk];
            float4 a1 = *(const float4*)&xs[(r0 + 1) * 100 + kk];
            float4 a2 = *(const float4*)&xs[(r0 + 2) * 100 + kk];
            float4 a3 = *(const float4*)&xs[(r0 + 3) * 100 + kk];
            uint2 u0 = *(const uint2*)&wsp[(kk + 0) * 48 + je * 2];
            uint2 u1 = *(const uint2*)&wsp[(kk + 1) * 48 + je * 2];
            uint2 u2 = *(const uint2*)&wsp[(kk + 2) * 48 + je * 2];
            uint2 u3 = *(const uint2*)&wsp[(kk + 3) * 48 + je * 2];
            float4 w0 = make_float4(unlo(u0.x), unhi(u0.x), unlo(u0.y), unhi(u0.y));
            float4 w1 = make_float4(unlo(u1.x), unhi(u1.x), unlo(u1.y), unhi(u1.y));
            float4 w2 = make_float4(unlo(u2.x), unhi(u2.x), unlo(u2.y), unhi(u2.y));
            float4 w3 = make_float4(unlo(u3.x), unhi(u3.x), unlo(u3.y), unhi(u3.y));
#define ROWFMA(i, a)                                                                  \
    acc[i][0] = fmaf(a.x, w0.x, fmaf(a.y, w1.x, fmaf(a.z, w2.x, fmaf(a.w, w3.x, acc[i][0])))); \
    acc[i][1] = fmaf(a.x, w0.y, fmaf(a.y, w1.y, fmaf(a.z, w2.y, fmaf(a.w, w3.y, acc[i][1])))); \
    acc[i][2] = fmaf(a.x, w0.z, fmaf(a.y, w1.z, fmaf(a.z, w2.z, fmaf(a.w, w3.z, acc[i][2])))); \
    acc[i][3] = fmaf(a.x, w0.w, fmaf(a.y, w1.w, fmaf(a.z, w2.w, fmaf(a.w, w3.w, acc[i][3]))));
            ROWFMA(0, a0) ROWFMA(1, a1) ROWFMA(2, a2) ROWFMA(3, a3)
#undef ROWFMA
        }
        const float* Bm = Bs[m];
        const float bb0 = Bm[j0], bb1 = Bm[j0 + 1], bb2 = Bm[j0 + 2], bb3 = Bm[j0 + 3];
#pragma unroll
        for (int i = 0; i < 4; ++i) {
            int row = row0 + r0 + i;
            if (row >= nrows) continue;
            float v0 = acc[i][0] + bb0, v1 = acc[i][1] + bb1;
            float v2 = acc[i][2] + bb2, v3 = acc[i][3] + bb3;
            if (m == 0) {
                *(float4*)&Y0[(long)row * DD + j0] = make_float4(v0, v1, v2, v3);
            } else {
                u16* Yp = (m == 1) ? Y1 : ((m == 2) ? Y2 : Y3);
                *(uint2*)&Yp[(long)row * DD + j0] = make_uint2(pk2(v0, v1), pk2(v2, v3));
            }
        }
        __syncthreads();   // wsp reused next m
    }
}

// Per-destination-node fused edge+aggregate kernel (edges sorted by dst).
// Cw staged as packed bf16 (18 KB) -> ~31.5 KB LDS -> 5 blocks/CU.
__global__ __launch_bounds__(192) void k_node_edge(u16* ebuf,
                                                   const float* __restrict__ Cw,
                                                   const float* __restrict__ Cb,
                                                   const u16* __restrict__ Dh,
                                                   const u16* __restrict__ Eh,
                                                   const u16* __restrict__ Bh,
                                                   const int* __restrict__ srcp,
                                                   const int* __restrict__ row_ptr,
                                                   const float* __restrict__ Ah,
                                                   float* __restrict__ hbuf) {
    __shared__ u32 cwp[DD * 48];      // 18 KB bf16-packed Cw
    __shared__ float xs[16 * 100];    // 6.4 KB
    __shared__ float redn[8][DD];     // 3 KB
    __shared__ float redd[8][DD];     // 3 KB
    __shared__ float sehn[DD];
    __shared__ float scb[DD];
    __shared__ int ssrc[16];
    const int tid = threadIdx.x;
    const int n = blockIdx.x;
    const int r0 = row_ptr[n], r1 = row_ptr[n + 1];
    {
        const float4* Wv = (const float4*)Cw;
        uint2* wv = (uint2*)cwp;
#pragma unroll
        for (int t = 0; t < 12; ++t) {
            float4 v = Wv[tid + t * 192];
            wv[tid + t * 192] = make_uint2(pk2(v.x, v.y), pk2(v.z, v.w));
        }
    }
    if (tid < DD) sehn[tid] = bf2f(Eh[(long)n * DD + tid]);
    else if (tid < 2 * DD) scb[tid - DD] = Cb[tid - DD];
    const int je = tid % 24, ge = tid / 24;
    const int j0 = je * 4, rl0 = ge * 2;
    float s_num[4] = {0.f, 0.f, 0.f, 0.f};
    float s_den[4] = {0.f, 0.f, 0.f, 0.f};
    __syncthreads();

    for (int chunk = r0; chunk < r1; chunk += 16) {
        const int rows = min(16, r1 - chunk);
#pragma unroll
        for (int t = 0; t < 2; ++t) {
            int q = tid + t * 192;
            int r = q / 24, c4 = q - r * 24;
            float* xp = &xs[r * 100 + c4 * 4];
            if (r < rows) {
                uint2 u = *(const uint2*)&ebuf[(long)(chunk + r) * DD + c4 * 4];
                xp[0] = unlo(u.x); xp[1] = unhi(u.x);
                xp[2] = unlo(u.y); xp[3] = unhi(u.y);
            } else {
                xp[0] = 0.f; xp[1] = 0.f; xp[2] = 0.f; xp[3] = 0.f;
            }
        }
        if (tid < 16) ssrc[tid] = (chunk + tid < r1) ? srcp[chunk + tid] : 0;
        __syncthreads();
        float acc[2][4] = {};
#pragma unroll 4
        for (int k4 = 0; k4 < 24; ++k4) {
            const int kk = k4 * 4;
            float4 a0 = *(const float4*)&xs[(rl0 + 0) * 100 + kk];
            float4 a1 = *(const float4*)&xs[(rl0 + 1) * 100 + kk];
            uint2 u0 = *(const uint2*)&cwp[(kk + 0) * 48 + je * 2];
            uint2 u1 = *(const uint2*)&cwp[(kk + 1) * 48 + je * 2];
            uint2 u2 = *(const uint2*)&cwp[(kk + 2) * 48 + je * 2];
            uint2 u3 = *(const uint2*)&cwp[(kk + 3) * 48 + je * 2];
            float4 w0 = make_float4(unlo(u0.x), unhi(u0.x), unlo(u0.y), unhi(u0.y));
            float4 w1 = make_float4(unlo(u1.x), unhi(u1.x), unlo(u1.y), unhi(u1.y));
            float4 w2 = make_float4(unlo(u2.x), unhi(u2.x), unlo(u2.y), unhi(u2.y));
            float4 w3 = make_float4(unlo(u3.x), unhi(u3.x), unlo(u3.y), unhi(u3.y));
#define ROWFMA(i, a)                                                                  \
    acc[i][0] = fmaf(a.x, w0.x, fmaf(a.y, w1.x, fmaf(a.z, w2.x, fmaf(a.w, w3.x, acc[i][0])))); \
    acc[i][1] = fmaf(a.x, w0.y, fmaf(a.y, w1.y, fmaf(a.z, w2.y, fmaf(a.w, w3.y, acc[i][1])))); \
    acc[i][2] = fmaf(a.x, w0.z, fmaf(a.y, w1.z, fmaf(a.z, w2.z, fmaf(a.w, w3.z, acc[i][2])))); \
    acc[i][3] = fmaf(a.x, w0.w, fmaf(a.y, w1.w, fmaf(a.z, w2.w, fmaf(a.w, w3.w, acc[i][3]))));
            ROWFMA(0, a0) ROWFMA(1, a1)
#undef ROWFMA
        }
#pragma unroll
        for (int i = 0; i < 2; ++i) {
            const int rl = rl0 + i;
            if (rl < rows) {
                const long eg = chunk + rl;
                const int s = ssrc[rl];
                const uint2 du = *(const uint2*)&Dh[(long)s * DD + j0];
                const uint2 bu = *(const uint2*)&Bh[(long)s * DD + j0];
                float en0 = acc[i][0] + scb[j0 + 0] + unlo(du.x) + sehn[j0 + 0];
                float en1 = acc[i][1] + scb[j0 + 1] + unhi(du.x) + sehn[j0 + 1];
                float en2 = acc[i][2] + scb[j0 + 2] + unlo(du.y) + sehn[j0 + 2];
                float en3 = acc[i][3] + scb[j0 + 3] + unhi(du.y) + sehn[j0 + 3];
                float sg0 = 1.f / (1.f + __expf(-en0));
                float sg1 = 1.f / (1.f + __expf(-en1));
                float sg2 = 1.f / (1.f + __expf(-en2));
                float sg3 = 1.f / (1.f + __expf(-en3));
                s_num[0] += unlo(bu.x) * sg0; s_den[0] += sg0;
                s_num[1] += unhi(bu.x) * sg1; s_den[1] += sg1;
                s_num[2] += unlo(bu.y) * sg2; s_den[2] += sg2;
                s_num[3] += unhi(bu.y) * sg3; s_den[3] += sg3;
                const float* xp = &xs[rl * 100 + j0];
                float o0 = xp[0] + fmaxf(en0, 0.f), o1 = xp[1] + fmaxf(en1, 0.f);
                float o2 = xp[2] + fmaxf(en2, 0.f), o3 = xp[3] + fmaxf(en3, 0.f);
                *(uint2*)&ebuf[eg * DD + j0] = make_uint2(pk2(o0, o1), pk2(o2, o3));
            }
        }
        __syncthreads();   // xs reused next chunk
    }
#pragma unroll
    for (int c = 0; c < 4; ++c) { redn[ge][j0 + c] = s_num[c]; redd[ge][j0 + c] = s_den[c]; }
    __syncthreads();
    if (tid < DD) {
        float num = 0.f, den = 0.f;
#pragma unroll
        for (int g = 0; g < 8; ++g) { num += redn[g][tid]; den += redd[g][tid]; }
        float val = Ah[(long)n * DD + tid] + num / (den + EPSF);
        hbuf[(long)n * DD + tid] += fmaxf(val, 0.f);
    }
}

// small MLP stage, one thread per output element
__global__ void k_mlp(const float* __restrict__ X, const float* __restrict__ W,
                      const float* __restrict__ B, float* __restrict__ Y,
                      int K, int Dout, int act, long total) {
    long idx = (long)blockIdx.x * blockDim.x + threadIdx.x;
    if (idx >= total) return;
    int row = (int)(idx / Dout);
    int j = (int)(idx - (long)row * Dout);
    const float* xr = X + (long)row * K;
    float acc = B[j];
    for (int k = 0; k < K; ++k) acc = fmaf(xr[k], W[k * Dout + j], acc);
    if (act == 1) acc = fmaxf(acc, 0.f);
    else if (act == 2) acc = 1.f / (1.f + __expf(-acc));
    Y[idx] = acc;
}

extern "C" void kernel_launch(void* const* d_in, const int* in_sizes, int n_in,
                              void* d_out, int out_size, void* d_ws, size_t ws_size,
                              hipStream_t stream) {
    const float* h_in = (const float*)d_in[0];
    const float* e_in = (const float*)d_in[1];
    const int* src = (const int*)d_in[2];
    const int* dst = (const int*)d_in[3];
    const float* fp_w = (const float*)d_in[4];
    const float* fp_b = (const float*)d_in[5];
    const float* ep_w = (const float*)d_in[6];
    const float* ep_b = (const float*)d_in[7];
    const float* A_w = (const float*)d_in[8];
    const float* A_b = (const float*)d_in[9];
    const float* B_w = (const float*)d_in[10];
    const float* B_b = (const float*)d_in[11];
    const float* C_w = (const float*)d_in[12];
    const float* C_b = (const float*)d_in[13];
    const float* D_w = (const float*)d_in[14];
    const float* D_b = (const float*)d_in[15];
    const float* E_w = (const float*)d_in[16];
    const float* E_b = (const float*)d_in[17];
    const float* mlp0_w = (const float*)d_in[18];
    const float* mlp0_b = (const float*)d_in[19];
    const float* mlp1_w = (const float*)d_in[20];
    const float* mlp1_b = (const float*)d_in[21];
    const float* mlp2_w = (const float*)d_in[22];
    const float* mlp2_b = (const float*)d_in[23];
    float* out = (float*)d_out;

    const size_t ND = (size_t)NN * DD;
    const size_t ED = (size_t)NE * DD;
    char* w = (char*)d_ws;
    float* hbuf = (float*)w; w += ND * 4;
    float* Ahb  = (float*)w; w += ND * 4;
    u16* Bhb = (u16*)w; w += ND * 2;
    u16* Dhb = (u16*)w; w += ND * 2;
    u16* Ehb = (u16*)w; w += ND * 2;
    u16* ebuf = (u16*)w; w += ED * 2;
    int* counts  = (int*)w; w += (size_t)NN * 4;
    int* row_ptr = (int*)w; w += (size_t)(NN + 1) * 4 + 12;  // keep 16B align after
    int* cursor  = (int*)w; w += (size_t)NN * 4;
    int* eperm   = (int*)w; w += (size_t)NE * 4;
    int* srcp    = (int*)w; w += (size_t)NE * 4;
    size_t need = (size_t)(w - (char*)d_ws);
    if (ws_size < need) return;  // uniform -> graph-safe; fails absmax as diagnostic

    // CSR build (dst-sorted edge permutation)
    k_zero_i<<<(NN + 255) / 256, 256, 0, stream>>>(counts, NN);
    k_hist<<<(NE + 255) / 256, 256, 0, stream>>>(dst, counts);
    k_scan<<<1, 1024, 0, stream>>>(counts, row_ptr, cursor, NN);
    k_scatter<<<(NE + 255) / 256, 256, 0, stream>>>(src, dst, cursor, eperm, srcp);

    // input projections (edge proj lands in dst-sorted order), LDS-tiled
    k_proj_t<false, false><<<(NN + 31) / 32, 192, 0, stream>>>(h_in, fp_w, fp_b, hbuf, nullptr, NN);
    k_proj_t<true, true><<<NE / 32, 192, 0, stream>>>(e_in, ep_w, ep_b, ebuf, eperm, NE);

    const int gN = (NN + 31) / 32;
    for (int l = 0; l < NL; ++l) {
        const float* Aw = A_w + (size_t)l * DD * DD; const float* Ab = A_b + (size_t)l * DD;
        const float* Bw = B_w + (size_t)l * DD * DD; const float* Bb = B_b + (size_t)l * DD;
        const float* Cw = C_w + (size_t)l * DD * DD; const float* Cb = C_b + (size_t)l * DD;
        const float* Dw = D_w + (size_t)l * DD * DD; const float* Db = D_b + (size_t)l * DD;
        const float* Ew = E_w + (size_t)l * DD * DD; const float* Eb = E_b + (size_t)l * DD;

        k_gemm4<<<gN, 192, 0, stream>>>(hbuf, Aw, Ab, Bw, Bb, Dw, Db, Ew, Eb,
                                        Ahb, Bhb, Dhb, Ehb, NN);
        k_node_edge<<<NN, 192, 0, stream>>>(ebuf, Cw, Cb, Dhb, Ehb, Bhb, srcp, row_ptr,
                                            Ahb, hbuf);
    }

    // MLP readout: 96 -> 48 (relu) -> 24 (relu) -> 10 (sigmoid). Reuse Ahb as temps.
    float* y1 = Ahb;                    // [N,48]
    float* y2 = Ahb + (size_t)NN * 48;  // [N,24]
    long t0 = (long)NN * 48, t1 = (long)NN * 24, t2 = (long)NN * NCLS;
    k_mlp<<<(int)((t0 + 255) / 256), 256, 0, stream>>>(hbuf, mlp0_w, mlp0_b, y1, DD, 48, 1, t0);
    k_mlp<<<(int)((t1 + 255) / 256), 256, 0, stream>>>(y1, mlp1_w, mlp1_b, y2, 48, 24, 1, t1);
    k_mlp<<<(int)((t2 + 255) / 256), 256, 0, stream>>>(y2, mlp2_w, mlp2_b, out, 24, NCLS, 2, t2);
}

// Round 7
// 2638.692 us; speedup vs baseline: 1.6059x; 1.2250x over previous
//
#include <hip/hip_runtime.h>

#define NN 50000
#define NE 800000
#define DIN 32
#define DD 96
#define NL 4
#define NCLS 10
#define EPSF 1e-6f

typedef unsigned short u16;
typedef unsigned int u32;

typedef __bf16 bf16x8 __attribute__((ext_vector_type(8)));
typedef float f32x4 __attribute__((ext_vector_type(4)));

static __device__ __forceinline__ float bf2f(u16 u) {
    return __uint_as_float(((u32)u) << 16);
}
static __device__ __forceinline__ u16 f2bf(float f) {
    u32 x = __float_as_uint(f);
    x += 0x7FFFu + ((x >> 16) & 1u);   // round-to-nearest-even
    return (u16)(x >> 16);
}
static __device__ __forceinline__ u32 pk2(float a, float b) {
    return (u32)f2bf(a) | ((u32)f2bf(b) << 16);
}
static __device__ __forceinline__ float unlo(u32 u) { return __uint_as_float(u << 16); }
static __device__ __forceinline__ float unhi(u32 u) { return __uint_as_float(u & 0xFFFF0000u); }

__global__ void k_zero_i(int* __restrict__ p, int n) {
    int i = blockIdx.x * blockDim.x + threadIdx.x;
    if (i < n) p[i] = 0;
}

__global__ void k_hist(const int* __restrict__ dst, int* __restrict__ counts) {
    int i = blockIdx.x * blockDim.x + threadIdx.x;
    if (i < NE) atomicAdd(&counts[dst[i]], 1);
}

// single-block exclusive scan over n counts -> row_ptr[0..n], cursor copy.
__global__ __launch_bounds__(1024) void k_scan(const int* __restrict__ counts,
                                               int* __restrict__ row_ptr,
                                               int* __restrict__ cursor, int n) {
    __shared__ int wsum[16];
    __shared__ int carry_s;
    const int tid = threadIdx.x;
    const int lane = tid & 63, wid = tid >> 6;
    if (tid == 0) carry_s = 0;
    __syncthreads();
    for (int base = 0; base < n; base += 1024) {
        int i = base + tid;
        int v = (i < n) ? counts[i] : 0;
        int x = v;
#pragma unroll
        for (int off = 1; off < 64; off <<= 1) {
            int t = __shfl_up(x, (unsigned)off, 64);
            if (lane >= off) x += t;
        }
        if (lane == 63) wsum[wid] = x;
        __syncthreads();
        if (wid == 0 && lane < 16) {
            int s = wsum[lane];
#pragma unroll
            for (int off = 1; off < 16; off <<= 1) {
                int t = __shfl_up(s, (unsigned)off, 16);
                if (lane >= off) s += t;
            }
            wsum[lane] = s;
        }
        __syncthreads();
        int wbase = (wid > 0) ? wsum[wid - 1] : 0;
        int carry = carry_s;
        int excl = carry + wbase + x - v;
        if (i < n) { row_ptr[i] = excl; cursor[i] = excl; }
        __syncthreads();
        if (tid == 0) carry_s = carry + wsum[15];
        __syncthreads();
    }
    if (tid == 0) row_ptr[n] = carry_s;
}

__global__ void k_scatter(const int* __restrict__ src, const int* __restrict__ dst,
                          int* __restrict__ cursor, int* __restrict__ eperm,
                          int* __restrict__ srcp) {
    int i = blockIdx.x * blockDim.x + threadIdx.x;
    if (i >= NE) return;
    int pos = atomicAdd(&cursor[dst[i]], 1);
    eperm[pos] = i;
    srcp[pos] = src[i];
}

// Tiled input projection: Y[row,:] = X[permrow,:DIN] @ W[DIN,DD] + B
template <bool BFOUT, bool PERM>
__global__ __launch_bounds__(192) void k_proj_t(const float* __restrict__ X,
                                                const float* __restrict__ W,
                                                const float* __restrict__ B,
                                                void* __restrict__ Y,
                                                const int* __restrict__ eperm,
                                                int nrows) {
    __shared__ float ws_w[DIN * DD];   // 12 KB, [k][j]
    __shared__ float xs[32][DIN + 1];
    const int tid = threadIdx.x;
    const int row0 = blockIdx.x * 32;
    {
        const float4* Wv = (const float4*)W;
        float4* wv = (float4*)ws_w;
#pragma unroll
        for (int t = 0; t < 4; ++t) wv[tid + t * 192] = Wv[tid + t * 192];
    }
    {
#pragma unroll
        for (int t = 0; t < 2; ++t) {
            int q = tid + t * 192;
            if (q < 256) {
                int r = q >> 3, c4 = q & 7;
                int grow = row0 + r;
                float4 v = make_float4(0.f, 0.f, 0.f, 0.f);
                if (grow < nrows) {
                    long srow = PERM ? (long)eperm[grow] : (long)grow;
                    v = *(const float4*)&X[srow * DIN + c4 * 4];
                }
                xs[r][c4 * 4 + 0] = v.x; xs[r][c4 * 4 + 1] = v.y;
                xs[r][c4 * 4 + 2] = v.z; xs[r][c4 * 4 + 3] = v.w;
            }
        }
    }
    __syncthreads();
    const int je = tid % 24, ge = tid / 24;
    const int j0 = je * 4, r0 = ge * 4;
    float acc[4][4] = {};
#pragma unroll
    for (int kk = 0; kk < DIN; kk += 4) {
        float4 w0 = *(const float4*)&ws_w[(kk + 0) * DD + j0];
        float4 w1 = *(const float4*)&ws_w[(kk + 1) * DD + j0];
        float4 w2 = *(const float4*)&ws_w[(kk + 2) * DD + j0];
        float4 w3 = *(const float4*)&ws_w[(kk + 3) * DD + j0];
#pragma unroll
        for (int i = 0; i < 4; ++i) {
            const float a0 = xs[r0 + i][kk + 0], a1 = xs[r0 + i][kk + 1];
            const float a2 = xs[r0 + i][kk + 2], a3 = xs[r0 + i][kk + 3];
            acc[i][0] = fmaf(a0, w0.x, fmaf(a1, w1.x, fmaf(a2, w2.x, fmaf(a3, w3.x, acc[i][0]))));
            acc[i][1] = fmaf(a0, w0.y, fmaf(a1, w1.y, fmaf(a2, w2.y, fmaf(a3, w3.y, acc[i][1]))));
            acc[i][2] = fmaf(a0, w0.z, fmaf(a1, w1.z, fmaf(a2, w2.z, fmaf(a3, w3.z, acc[i][2]))));
            acc[i][3] = fmaf(a0, w0.w, fmaf(a1, w1.w, fmaf(a2, w2.w, fmaf(a3, w3.w, acc[i][3]))));
        }
    }
    const float b0 = B[j0], b1 = B[j0 + 1], b2 = B[j0 + 2], b3 = B[j0 + 3];
#pragma unroll
    for (int i = 0; i < 4; ++i) {
        int row = row0 + r0 + i;
        if (row >= nrows) continue;
        float v0 = acc[i][0] + b0, v1 = acc[i][1] + b1;
        float v2 = acc[i][2] + b2, v3 = acc[i][3] + b3;
        if (BFOUT) {
            *(uint2*)((u16*)Y + (long)row * DD + j0) = make_uint2(pk2(v0, v1), pk2(v2, v3));
        } else {
            *(float4*)((float*)Y + (long)row * DD + j0) = make_float4(v0, v1, v2, v3);
        }
    }
}

// Fused 4-way node GEMM (VALU path, unchanged from r6).
__global__ __launch_bounds__(192) void k_gemm4(const float* __restrict__ X,
                                               const float* __restrict__ W0, const float* __restrict__ b0,
                                               const float* __restrict__ W1, const float* __restrict__ b1,
                                               const float* __restrict__ W2, const float* __restrict__ b2,
                                               const float* __restrict__ W3, const float* __restrict__ b3,
                                               float* __restrict__ Y0, u16* __restrict__ Y1,
                                               u16* __restrict__ Y2, u16* __restrict__ Y3,
                                               int nrows) {
    __shared__ u32 wsp[DD * 48];
    __shared__ float xs[32 * 100];
    const int tid = threadIdx.x;
    const int row0 = blockIdx.x * 32;
#pragma unroll
    for (int t = 0; t < 4; ++t) {
        int q = tid + t * 192;
        int r = q / 24, c4 = q - r * 24;
        int row = row0 + r;
        float4 v = make_float4(0.f, 0.f, 0.f, 0.f);
        if (row < nrows) v = *(const float4*)&X[(long)row * DD + c4 * 4];
        *(float4*)&xs[r * 100 + c4 * 4] = v;
    }
    const float* Ws[4] = {W0, W1, W2, W3};
    const float* Bs[4] = {b0, b1, b2, b3};
    const int je = tid % 24, ge = tid / 24;
    const int j0 = je * 4, r0 = ge * 4;
    for (int m = 0; m < 4; ++m) {
        {
            const float4* Wv = (const float4*)Ws[m];
            uint2* wv = (uint2*)wsp;
#pragma unroll
            for (int t = 0; t < 12; ++t) {
                float4 v = Wv[tid + t * 192];
                wv[tid + t * 192] = make_uint2(pk2(v.x, v.y), pk2(v.z, v.w));
            }
        }
        __syncthreads();
        float acc[4][4] = {};
#pragma unroll 4
        for (int k4 = 0; k4 < 24; ++k4) {
            const int kk = k4 * 4;
            float4 a0 = *(const float4*)&xs[(r0 + 0) * 100 + kk];
            float4 a1 = *(const float4*)&xs[(r0 + 1) * 100 + kk];
            float4 a2 = *(const float4*)&xs[(r0 + 2) * 100 + kk];
            float4 a3 = *(const float4*)&xs[(r0 + 3) * 100 + kk];
            uint2 u0 = *(const uint2*)&wsp[(kk + 0) * 48 + je * 2];
            uint2 u1 = *(const uint2*)&wsp[(kk + 1) * 48 + je * 2];
            uint2 u2 = *(const uint2*)&wsp[(kk + 2) * 48 + je * 2];
            uint2 u3 = *(const uint2*)&wsp[(kk + 3) * 48 + je * 2];
            float4 w0 = make_float4(unlo(u0.x), unhi(u0.x), unlo(u0.y), unhi(u0.y));
            float4 w1 = make_float4(unlo(u1.x), unhi(u1.x), unlo(u1.y), unhi(u1.y));
            float4 w2 = make_float4(unlo(u2.x), unhi(u2.x), unlo(u2.y), unhi(u2.y));
            float4 w3 = make_float4(unlo(u3.x), unhi(u3.x), unlo(u3.y), unhi(u3.y));
#define ROWFMA(i, a)                                                                  \
    acc[i][0] = fmaf(a.x, w0.x, fmaf(a.y, w1.x, fmaf(a.z, w2.x, fmaf(a.w, w3.x, acc[i][0])))); \
    acc[i][1] = fmaf(a.x, w0.y, fmaf(a.y, w1.y, fmaf(a.z, w2.y, fmaf(a.w, w3.y, acc[i][1])))); \
    acc[i][2] = fmaf(a.x, w0.z, fmaf(a.y, w1.z, fmaf(a.z, w2.z, fmaf(a.w, w3.z, acc[i][2])))); \
    acc[i][3] = fmaf(a.x, w0.w, fmaf(a.y, w1.w, fmaf(a.z, w2.w, fmaf(a.w, w3.w, acc[i][3]))));
            ROWFMA(0, a0) ROWFMA(1, a1) ROWFMA(2, a2) ROWFMA(3, a3)
#undef ROWFMA
        }
        const float* Bm = Bs[m];
        const float bb0 = Bm[j0], bb1 = Bm[j0 + 1], bb2 = Bm[j0 + 2], bb3 = Bm[j0 + 3];
#pragma unroll
        for (int i = 0; i < 4; ++i) {
            int row = row0 + r0 + i;
            if (row >= nrows) continue;
            float v0 = acc[i][0] + bb0, v1 = acc[i][1] + bb1;
            float v2 = acc[i][2] + bb2, v3 = acc[i][3] + bb3;
            if (m == 0) {
                *(float4*)&Y0[(long)row * DD + j0] = make_float4(v0, v1, v2, v3);
            } else {
                u16* Yp = (m == 1) ? Y1 : ((m == 2) ? Y2 : Y3);
                *(uint2*)&Yp[(long)row * DD + j0] = make_uint2(pk2(v0, v1), pk2(v2, v3));
            }
        }
        __syncthreads();
    }
}

// Per-destination-node fused edge+aggregate kernel — MFMA edition.
// Cw^T staged bf16 [n][k] stride 104; e-tile staged bf16 [m][k] stride 104.
// 3 waves x 2 col-tiles; mfma_f32_16x16x32_bf16; epilogue in C-layout.
__global__ __launch_bounds__(192) void k_node_edge(u16* ebuf,
                                                   const float* __restrict__ Cw,
                                                   const float* __restrict__ Cb,
                                                   const u16* __restrict__ Dh,
                                                   const u16* __restrict__ Eh,
                                                   const u16* __restrict__ Bh,
                                                   const int* __restrict__ srcp,
                                                   const int* __restrict__ row_ptr,
                                                   const float* __restrict__ Ah,
                                                   float* __restrict__ hbuf) {
#define LSTR 104                      // padded k-stride (bf16 elems): 2-way-free banks
    __shared__ u16 cwt[DD * LSTR];    // 19.5 KB  Cw^T as bf16 [n][k]
    __shared__ u16 atile[16 * LSTR];  // 3.3 KB   e-tile bf16 [m][k]
    __shared__ float snum[DD], sden[DD];
    __shared__ float sehn[DD], scb[DD];
    __shared__ int ssrc[16];
    const int tid = threadIdx.x;
    const int n = blockIdx.x;
    const int r0 = row_ptr[n], r1 = row_ptr[n + 1];
    // stage Cw^T (transpose+pack): 2304 float4 reads, coalesced over n
#pragma unroll
    for (int t = 0; t < 12; ++t) {
        int e4 = tid + t * 192;
        int k = e4 / 24, n0 = (e4 - k * 24) * 4;
        float4 v = *(const float4*)&Cw[k * DD + n0];
        cwt[(n0 + 0) * LSTR + k] = f2bf(v.x);
        cwt[(n0 + 1) * LSTR + k] = f2bf(v.y);
        cwt[(n0 + 2) * LSTR + k] = f2bf(v.z);
        cwt[(n0 + 3) * LSTR + k] = f2bf(v.w);
    }
    if (tid < DD) sehn[tid] = bf2f(Eh[(long)n * DD + tid]);
    else if (tid < 2 * DD) scb[tid - DD] = Cb[tid - DD];

    const int lane = tid & 63;
    const int wv = tid >> 6;          // wave 0..2 -> col tiles {2wv, 2wv+1}
    const int lm = lane & 15;
    const int quad = lane >> 4;
    const int srow = tid / 12, sc8 = tid - srow * 12;   // a-tile staging map
    float nacc[2] = {0.f, 0.f}, dacc[2] = {0.f, 0.f};
    __syncthreads();

    for (int chunk = r0; chunk < r1; chunk += 16) {
        const int rows = min(16, r1 - chunk);
        // stage 16 e-rows (bf16, 16B per thread)
        if (srow < rows) {
            uint4 u = *(const uint4*)&ebuf[(long)(chunk + srow) * DD + sc8 * 8];
            *(uint4*)&atile[srow * LSTR + sc8 * 8] = u;
        } else {
            *(uint4*)&atile[srow * LSTR + sc8 * 8] = make_uint4(0, 0, 0, 0);
        }
        if (tid < 16) ssrc[tid] = (chunk + tid < r1) ? srcp[chunk + tid] : 0;
        __syncthreads();

        f32x4 acc0 = {0.f, 0.f, 0.f, 0.f}, acc1 = {0.f, 0.f, 0.f, 0.f};
#pragma unroll
        for (int c = 0; c < 3; ++c) {
            bf16x8 a  = *(const bf16x8*)&atile[lm * LSTR + c * 32 + quad * 8];
            bf16x8 b0 = *(const bf16x8*)&cwt[((2 * wv + 0) * 16 + lm) * LSTR + c * 32 + quad * 8];
            bf16x8 b1 = *(const bf16x8*)&cwt[((2 * wv + 1) * 16 + lm) * LSTR + c * 32 + quad * 8];
            acc0 = __builtin_amdgcn_mfma_f32_16x16x32_bf16(a, b0, acc0, 0, 0, 0);
            acc1 = __builtin_amdgcn_mfma_f32_16x16x32_bf16(a, b1, acc1, 0, 0, 0);
        }
        // epilogue: lane = col j, 4 edge-rows (C layout: col=lane&15, row=quad*4+reg)
#pragma unroll
        for (int t = 0; t < 2; ++t) {
            const int j = (2 * wv + t) * 16 + lm;
            const float cbj = scb[j], ehj = sehn[j];
#pragma unroll
            for (int r = 0; r < 4; ++r) {
                const int rl = quad * 4 + r;
                if (rl < rows) {
                    const int s = ssrc[rl];
                    float dh = bf2f(Dh[(long)s * DD + j]);
                    float bh = bf2f(Bh[(long)s * DD + j]);
                    float en = (t ? acc1[r] : acc0[r]) + cbj + dh + ehj;
                    float sg = 1.f / (1.f + __expf(-en));
                    nacc[t] += bh * sg;
                    dacc[t] += sg;
                    float old = bf2f(atile[rl * LSTR + j]);
                    ebuf[(long)(chunk + rl) * DD + j] = f2bf(old + fmaxf(en, 0.f));
                }
            }
        }
        __syncthreads();   // atile reused next chunk
    }
    // reduce num/den over quads (butterfly), stash per-col sums
#pragma unroll
    for (int t = 0; t < 2; ++t) {
        float x = nacc[t], y = dacc[t];
        x += __shfl_xor(x, 16); y += __shfl_xor(y, 16);
        x += __shfl_xor(x, 32); y += __shfl_xor(y, 32);
        if (lane < 16) { snum[(2 * wv + t) * 16 + lane] = x; sden[(2 * wv + t) * 16 + lane] = y; }
    }
    __syncthreads();
    if (tid < DD) {
        float val = Ah[(long)n * DD + tid] + snum[tid] / (sden[tid] + EPSF);
        hbuf[(long)n * DD + tid] += fmaxf(val, 0.f);
    }
#undef LSTR
}

// small MLP stage, one thread per output element
__global__ void k_mlp(const float* __restrict__ X, const float* __restrict__ W,
                      const float* __restrict__ B, float* __restrict__ Y,
                      int K, int Dout, int act, long total) {
    long idx = (long)blockIdx.x * blockDim.x + threadIdx.x;
    if (idx >= total) return;
    int row = (int)(idx / Dout);
    int j = (int)(idx - (long)row * Dout);
    const float* xr = X + (long)row * K;
    float acc = B[j];
    for (int k = 0; k < K; ++k) acc = fmaf(xr[k], W[k * Dout + j], acc);
    if (act == 1) acc = fmaxf(acc, 0.f);
    else if (act == 2) acc = 1.f / (1.f + __expf(-acc));
    Y[idx] = acc;
}

extern "C" void kernel_launch(void* const* d_in, const int* in_sizes, int n_in,
                              void* d_out, int out_size, void* d_ws, size_t ws_size,
                              hipStream_t stream) {
    const float* h_in = (const float*)d_in[0];
    const float* e_in = (const float*)d_in[1];
    const int* src = (const int*)d_in[2];
    const int* dst = (const int*)d_in[3];
    const float* fp_w = (const float*)d_in[4];
    const float* fp_b = (const float*)d_in[5];
    const float* ep_w = (const float*)d_in[6];
    const float* ep_b = (const float*)d_in[7];
    const float* A_w = (const float*)d_in[8];
    const float* A_b = (const float*)d_in[9];
    const float* B_w = (const float*)d_in[10];
    const float* B_b = (const float*)d_in[11];
    const float* C_w = (const float*)d_in[12];
    const float* C_b = (const float*)d_in[13];
    const float* D_w = (const float*)d_in[14];
    const float* D_b = (const float*)d_in[15];
    const float* E_w = (const float*)d_in[16];
    const float* E_b = (const float*)d_in[17];
    const float* mlp0_w = (const float*)d_in[18];
    const float* mlp0_b = (const float*)d_in[19];
    const float* mlp1_w = (const float*)d_in[20];
    const float* mlp1_b = (const float*)d_in[21];
    const float* mlp2_w = (const float*)d_in[22];
    const float* mlp2_b = (const float*)d_in[23];
    float* out = (float*)d_out;

    const size_t ND = (size_t)NN * DD;
    const size_t ED = (size_t)NE * DD;
    char* w = (char*)d_ws;
    float* hbuf = (float*)w; w += ND * 4;
    float* Ahb  = (float*)w; w += ND * 4;
    u16* Bhb = (u16*)w; w += ND * 2;
    u16* Dhb = (u16*)w; w += ND * 2;
    u16* Ehb = (u16*)w; w += ND * 2;
    u16* ebuf = (u16*)w; w += ED * 2;
    int* counts  = (int*)w; w += (size_t)NN * 4;
    int* row_ptr = (int*)w; w += (size_t)(NN + 1) * 4 + 12;
    int* cursor  = (int*)w; w += (size_t)NN * 4;
    int* eperm   = (int*)w; w += (size_t)NE * 4;
    int* srcp    = (int*)w; w += (size_t)NE * 4;
    size_t need = (size_t)(w - (char*)d_ws);
    if (ws_size < need) return;  // uniform -> graph-safe; fails absmax as diagnostic

    // CSR build (dst-sorted edge permutation)
    k_zero_i<<<(NN + 255) / 256, 256, 0, stream>>>(counts, NN);
    k_hist<<<(NE + 255) / 256, 256, 0, stream>>>(dst, counts);
    k_scan<<<1, 1024, 0, stream>>>(counts, row_ptr, cursor, NN);
    k_scatter<<<(NE + 255) / 256, 256, 0, stream>>>(src, dst, cursor, eperm, srcp);

    // input projections (edge proj lands in dst-sorted order), LDS-tiled
    k_proj_t<false, false><<<(NN + 31) / 32, 192, 0, stream>>>(h_in, fp_w, fp_b, hbuf, nullptr, NN);
    k_proj_t<true, true><<<NE / 32, 192, 0, stream>>>(e_in, ep_w, ep_b, ebuf, eperm, NE);

    const int gN = (NN + 31) / 32;
    for (int l = 0; l < NL; ++l) {
        const float* Aw = A_w + (size_t)l * DD * DD; const float* Ab = A_b + (size_t)l * DD;
        const float* Bw = B_w + (size_t)l * DD * DD; const float* Bb = B_b + (size_t)l * DD;
        const float* Cw = C_w + (size_t)l * DD * DD; const float* Cb = C_b + (size_t)l * DD;
        const float* Dw = D_w + (size_t)l * DD * DD; const float* Db = D_b + (size_t)l * DD;
        const float* Ew = E_w + (size_t)l * DD * DD; const float* Eb = E_b + (size_t)l * DD;

        k_gemm4<<<gN, 192, 0, stream>>>(hbuf, Aw, Ab, Bw, Bb, Dw, Db, Ew, Eb,
                                        Ahb, Bhb, Dhb, Ehb, NN);
        k_node_edge<<<NN, 192, 0, stream>>>(ebuf, Cw, Cb, Dhb, Ehb, Bhb, srcp, row_ptr,
                                            Ahb, hbuf);
    }

    // MLP readout: 96 -> 48 (relu) -> 24 (relu) -> 10 (sigmoid). Reuse Ahb as temps.
    float* y1 = Ahb;
    float* y2 = Ahb + (size_t)NN * 48;
    long t0 = (long)NN * 48, t1 = (long)NN * 24, t2 = (long)NN * NCLS;
    k_mlp<<<(int)((t0 + 255) / 256), 256, 0, stream>>>(hbuf, mlp0_w, mlp0_b, y1, DD, 48, 1, t0);
    k_mlp<<<(int)((t1 + 255) / 256), 256, 0, stream>>>(y1, mlp1_w, mlp1_b, y2, 48, 24, 1, t1);
    k_mlp<<<(int)((t2 + 255) / 256), 256, 0, stream>>>(y2, mlp2_w, mlp2_b, out, 24, NCLS, 2, t2);
}

// Round 8
// 2022.892 us; speedup vs baseline: 2.0948x; 1.3044x over previous
//
#include <hip/hip_runtime.h>

#define NN 50000
#define NE 800000
#define DIN 32
#define DD 96
#define NL 4
#define NCLS 10
#define EPSF 1e-6f

typedef unsigned short u16;
typedef unsigned int u32;

typedef __bf16 bf16x8 __attribute__((ext_vector_type(8)));
typedef float f32x4 __attribute__((ext_vector_type(4)));

static __device__ __forceinline__ float bf2f(u16 u) {
    return __uint_as_float(((u32)u) << 16);
}
static __device__ __forceinline__ u16 f2bf(float f) {
    u32 x = __float_as_uint(f);
    x += 0x7FFFu + ((x >> 16) & 1u);   // round-to-nearest-even
    return (u16)(x >> 16);
}
static __device__ __forceinline__ u32 pk2(float a, float b) {
    return (u32)f2bf(a) | ((u32)f2bf(b) << 16);
}
static __device__ __forceinline__ float unlo(u32 u) { return __uint_as_float(u << 16); }
static __device__ __forceinline__ float unhi(u32 u) { return __uint_as_float(u & 0xFFFF0000u); }

__global__ void k_zero_i(int* __restrict__ p, int n) {
    int i = blockIdx.x * blockDim.x + threadIdx.x;
    if (i < n) p[i] = 0;
}

__global__ void k_hist(const int* __restrict__ dst, int* __restrict__ counts) {
    int i = blockIdx.x * blockDim.x + threadIdx.x;
    if (i < NE) atomicAdd(&counts[dst[i]], 1);
}

// single-block exclusive scan over n counts -> row_ptr[0..n], cursor copy.
__global__ __launch_bounds__(1024) void k_scan(const int* __restrict__ counts,
                                               int* __restrict__ row_ptr,
                                               int* __restrict__ cursor, int n) {
    __shared__ int wsum[16];
    __shared__ int carry_s;
    const int tid = threadIdx.x;
    const int lane = tid & 63, wid = tid >> 6;
    if (tid == 0) carry_s = 0;
    __syncthreads();
    for (int base = 0; base < n; base += 1024) {
        int i = base + tid;
        int v = (i < n) ? counts[i] : 0;
        int x = v;
#pragma unroll
        for (int off = 1; off < 64; off <<= 1) {
            int t = __shfl_up(x, (unsigned)off, 64);
            if (lane >= off) x += t;
        }
        if (lane == 63) wsum[wid] = x;
        __syncthreads();
        if (wid == 0 && lane < 16) {
            int s = wsum[lane];
#pragma unroll
            for (int off = 1; off < 16; off <<= 1) {
                int t = __shfl_up(s, (unsigned)off, 16);
                if (lane >= off) s += t;
            }
            wsum[lane] = s;
        }
        __syncthreads();
        int wbase = (wid > 0) ? wsum[wid - 1] : 0;
        int carry = carry_s;
        int excl = carry + wbase + x - v;
        if (i < n) { row_ptr[i] = excl; cursor[i] = excl; }
        __syncthreads();
        if (tid == 0) carry_s = carry + wsum[15];
        __syncthreads();
    }
    if (tid == 0) row_ptr[n] = carry_s;
}

__global__ void k_scatter(const int* __restrict__ src, const int* __restrict__ dst,
                          int* __restrict__ cursor, int* __restrict__ eperm,
                          int* __restrict__ srcp) {
    int i = blockIdx.x * blockDim.x + threadIdx.x;
    if (i >= NE) return;
    int pos = atomicAdd(&cursor[dst[i]], 1);
    eperm[pos] = i;
    srcp[pos] = src[i];
}

// Pack all 4 layers' Cw into MFMA B-fragment order (bf16):
// cwf[l][tile][c][lane][j] = bf16(Cw[l][k=c*32+(lane>>4)*8+j][n=tile*16+(lane&15)])
__global__ void k_packCw(const float* __restrict__ Cw_all, u16* __restrict__ cwf) {
    int q = blockIdx.x * blockDim.x + threadIdx.x;   // fragment index
    if (q >= NL * 6 * 3 * 64) return;
    int l = q / (6 * 3 * 64);
    int rem = q - l * (6 * 3 * 64);
    int tile = rem / (3 * 64);
    int rem2 = rem - tile * (3 * 64);
    int c = rem2 >> 6, lane = rem2 & 63;
    const float* Cw = Cw_all + (long)l * DD * DD;
    int n = tile * 16 + (lane & 15);
    int k0 = c * 32 + (lane >> 4) * 8;
    u16 w[8];
#pragma unroll
    for (int j = 0; j < 8; ++j) w[j] = f2bf(Cw[(k0 + j) * DD + n]);
    *(uint4*)&cwf[(long)q * 8] = *(uint4*)w;
}

// Tiled input projection: Y[row,:] = X[permrow,:DIN] @ W[DIN,DD] + B
template <bool BFOUT, bool PERM>
__global__ __launch_bounds__(192) void k_proj_t(const float* __restrict__ X,
                                                const float* __restrict__ W,
                                                const float* __restrict__ B,
                                                void* __restrict__ Y,
                                                const int* __restrict__ eperm,
                                                int nrows) {
    __shared__ float ws_w[DIN * DD];   // 12 KB, [k][j]
    __shared__ float xs[32][DIN + 1];
    const int tid = threadIdx.x;
    const int row0 = blockIdx.x * 32;
    {
        const float4* Wv = (const float4*)W;
        float4* wv = (float4*)ws_w;
#pragma unroll
        for (int t = 0; t < 4; ++t) wv[tid + t * 192] = Wv[tid + t * 192];
    }
    {
#pragma unroll
        for (int t = 0; t < 2; ++t) {
            int q = tid + t * 192;
            if (q < 256) {
                int r = q >> 3, c4 = q & 7;
                int grow = row0 + r;
                float4 v = make_float4(0.f, 0.f, 0.f, 0.f);
                if (grow < nrows) {
                    long srow = PERM ? (long)eperm[grow] : (long)grow;
                    v = *(const float4*)&X[srow * DIN + c4 * 4];
                }
                xs[r][c4 * 4 + 0] = v.x; xs[r][c4 * 4 + 1] = v.y;
                xs[r][c4 * 4 + 2] = v.z; xs[r][c4 * 4 + 3] = v.w;
            }
        }
    }
    __syncthreads();
    const int je = tid % 24, ge = tid / 24;
    const int j0 = je * 4, r0 = ge * 4;
    float acc[4][4] = {};
#pragma unroll
    for (int kk = 0; kk < DIN; kk += 4) {
        float4 w0 = *(const float4*)&ws_w[(kk + 0) * DD + j0];
        float4 w1 = *(const float4*)&ws_w[(kk + 1) * DD + j0];
        float4 w2 = *(const float4*)&ws_w[(kk + 2) * DD + j0];
        float4 w3 = *(const float4*)&ws_w[(kk + 3) * DD + j0];
#pragma unroll
        for (int i = 0; i < 4; ++i) {
            const float a0 = xs[r0 + i][kk + 0], a1 = xs[r0 + i][kk + 1];
            const float a2 = xs[r0 + i][kk + 2], a3 = xs[r0 + i][kk + 3];
            acc[i][0] = fmaf(a0, w0.x, fmaf(a1, w1.x, fmaf(a2, w2.x, fmaf(a3, w3.x, acc[i][0]))));
            acc[i][1] = fmaf(a0, w0.y, fmaf(a1, w1.y, fmaf(a2, w2.y, fmaf(a3, w3.y, acc[i][1]))));
            acc[i][2] = fmaf(a0, w0.z, fmaf(a1, w1.z, fmaf(a2, w2.z, fmaf(a3, w3.z, acc[i][2]))));
            acc[i][3] = fmaf(a0, w0.w, fmaf(a1, w1.w, fmaf(a2, w2.w, fmaf(a3, w3.w, acc[i][3]))));
        }
    }
    const float b0 = B[j0], b1 = B[j0 + 1], b2 = B[j0 + 2], b3 = B[j0 + 3];
#pragma unroll
    for (int i = 0; i < 4; ++i) {
        int row = row0 + r0 + i;
        if (row >= nrows) continue;
        float v0 = acc[i][0] + b0, v1 = acc[i][1] + b1;
        float v2 = acc[i][2] + b2, v3 = acc[i][3] + b3;
        if (BFOUT) {
            *(uint2*)((u16*)Y + (long)row * DD + j0) = make_uint2(pk2(v0, v1), pk2(v2, v3));
        } else {
            *(float4*)((float*)Y + (long)row * DD + j0) = make_float4(v0, v1, v2, v3);
        }
    }
}

// Fused 4-way node GEMM (VALU path).
__global__ __launch_bounds__(192) void k_gemm4(const float* __restrict__ X,
                                               const float* __restrict__ W0, const float* __restrict__ b0,
                                               const float* __restrict__ W1, const float* __restrict__ b1,
                                               const float* __restrict__ W2, const float* __restrict__ b2,
                                               const float* __restrict__ W3, const float* __restrict__ b3,
                                               float* __restrict__ Y0, u16* __restrict__ Y1,
                                               u16* __restrict__ Y2, u16* __restrict__ Y3,
                                               int nrows) {
    __shared__ u32 wsp[DD * 48];
    __shared__ float xs[32 * 100];
    const int tid = threadIdx.x;
    const int row0 = blockIdx.x * 32;
#pragma unroll
    for (int t = 0; t < 4; ++t) {
        int q = tid + t * 192;
        int r = q / 24, c4 = q - r * 24;
        int row = row0 + r;
        float4 v = make_float4(0.f, 0.f, 0.f, 0.f);
        if (row < nrows) v = *(const float4*)&X[(long)row * DD + c4 * 4];
        *(float4*)&xs[r * 100 + c4 * 4] = v;
    }
    const float* Ws[4] = {W0, W1, W2, W3};
    const float* Bs[4] = {b0, b1, b2, b3};
    const int je = tid % 24, ge = tid / 24;
    const int j0 = je * 4, r0 = ge * 4;
    for (int m = 0; m < 4; ++m) {
        {
            const float4* Wv = (const float4*)Ws[m];
            uint2* wv = (uint2*)wsp;
#pragma unroll
            for (int t = 0; t < 12; ++t) {
                float4 v = Wv[tid + t * 192];
                wv[tid + t * 192] = make_uint2(pk2(v.x, v.y), pk2(v.z, v.w));
            }
        }
        __syncthreads();
        float acc[4][4] = {};
#pragma unroll 4
        for (int k4 = 0; k4 < 24; ++k4) {
            const int kk = k4 * 4;
            float4 a0 = *(const float4*)&xs[(r0 + 0) * 100 + kk];
            float4 a1 = *(const float4*)&xs[(r0 + 1) * 100 + kk];
            float4 a2 = *(const float4*)&xs[(r0 + 2) * 100 + kk];
            float4 a3 = *(const float4*)&xs[(r0 + 3) * 100 + kk];
            uint2 u0 = *(const uint2*)&wsp[(kk + 0) * 48 + je * 2];
            uint2 u1 = *(const uint2*)&wsp[(kk + 1) * 48 + je * 2];
            uint2 u2 = *(const uint2*)&wsp[(kk + 2) * 48 + je * 2];
            uint2 u3 = *(const uint2*)&wsp[(kk + 3) * 48 + je * 2];
            float4 w0 = make_float4(unlo(u0.x), unhi(u0.x), unlo(u0.y), unhi(u0.y));
            float4 w1 = make_float4(unlo(u1.x), unhi(u1.x), unlo(u1.y), unhi(u1.y));
            float4 w2 = make_float4(unlo(u2.x), unhi(u2.x), unlo(u2.y), unhi(u2.y));
            float4 w3 = make_float4(unlo(u3.x), unhi(u3.x), unlo(u3.y), unhi(u3.y));
#define ROWFMA(i, a)                                                                  \
    acc[i][0] = fmaf(a.x, w0.x, fmaf(a.y, w1.x, fmaf(a.z, w2.x, fmaf(a.w, w3.x, acc[i][0])))); \
    acc[i][1] = fmaf(a.x, w0.y, fmaf(a.y, w1.y, fmaf(a.z, w2.y, fmaf(a.w, w3.y, acc[i][1])))); \
    acc[i][2] = fmaf(a.x, w0.z, fmaf(a.y, w1.z, fmaf(a.z, w2.z, fmaf(a.w, w3.z, acc[i][2])))); \
    acc[i][3] = fmaf(a.x, w0.w, fmaf(a.y, w1.w, fmaf(a.z, w2.w, fmaf(a.w, w3.w, acc[i][3]))));
            ROWFMA(0, a0) ROWFMA(1, a1) ROWFMA(2, a2) ROWFMA(3, a3)
#undef ROWFMA
        }
        const float* Bm = Bs[m];
        const float bb0 = Bm[j0], bb1 = Bm[j0 + 1], bb2 = Bm[j0 + 2], bb3 = Bm[j0 + 3];
#pragma unroll
        for (int i = 0; i < 4; ++i) {
            int row = row0 + r0 + i;
            if (row >= nrows) continue;
            float v0 = acc[i][0] + bb0, v1 = acc[i][1] + bb1;
            float v2 = acc[i][2] + bb2, v3 = acc[i][3] + bb3;
            if (m == 0) {
                *(float4*)&Y0[(long)row * DD + j0] = make_float4(v0, v1, v2, v3);
            } else {
                u16* Yp = (m == 1) ? Y1 : ((m == 2) ? Y2 : Y3);
                *(uint2*)&Yp[(long)row * DD + j0] = make_uint2(pk2(v0, v1), pk2(v2, v3));
            }
        }
        __syncthreads();
    }
}

// Per-destination-node fused edge+aggregate kernel — MFMA with register-resident
// B-fragments (pre-packed Cw). LDS only for the 16-edge A-tile + reductions.
__global__ __launch_bounds__(192) void k_node_edge(u16* ebuf,
                                                   const u16* __restrict__ cwf,  // [6][3][64][8]
                                                   const float* __restrict__ Cb,
                                                   const u16* __restrict__ Dh,
                                                   const u16* __restrict__ Eh,
                                                   const u16* __restrict__ Bh,
                                                   const int* __restrict__ srcp,
                                                   const int* __restrict__ row_ptr,
                                                   const float* __restrict__ Ah,
                                                   float* __restrict__ hbuf) {
#define LSTR 104
    __shared__ u16 atile[16 * LSTR];  // 3.3 KB  e-tile bf16 [m][k]
    __shared__ float snum[DD], sden[DD];
    __shared__ int ssrc[16];
    const int tid = threadIdx.x;
    const int n = blockIdx.x;
    const int r0 = row_ptr[n], r1 = row_ptr[n + 1];
    const int lane = tid & 63;
    const int wv = tid >> 6;          // wave 0..2 -> col tiles {2wv, 2wv+1}
    const int lm = lane & 15;
    const int quad = lane >> 4;
    const int srow = tid / 12, sc8 = tid - srow * 12;

    // B-fragments: 2 tiles x 3 K-steps, register-resident for the whole block
    bf16x8 bfrag[2][3];
#pragma unroll
    for (int t = 0; t < 2; ++t)
#pragma unroll
        for (int c = 0; c < 3; ++c)
            bfrag[t][c] = *(const bf16x8*)&cwf[(((long)(2 * wv + t) * 3 + c) * 64 + lane) * 8];

    // per-lane column constants: j = (2wv+t)*16 + lm
    const int j0c = (2 * wv + 0) * 16 + lm;
    const int j1c = (2 * wv + 1) * 16 + lm;
    const float cb0 = Cb[j0c], cb1 = Cb[j1c];
    const float eh0 = bf2f(Eh[(long)n * DD + j0c]);
    const float eh1 = bf2f(Eh[(long)n * DD + j1c]);
    float nacc[2] = {0.f, 0.f}, dacc[2] = {0.f, 0.f};

    for (int chunk = r0; chunk < r1; chunk += 16) {
        const int rows = min(16, r1 - chunk);
        if (srow < rows) {   // pad rows left stale: their C rows are never read
            uint4 u = *(const uint4*)&ebuf[(long)(chunk + srow) * DD + sc8 * 8];
            *(uint4*)&atile[srow * LSTR + sc8 * 8] = u;
        }
        if (tid < 16) ssrc[tid] = (chunk + tid < r1) ? srcp[chunk + tid] : 0;
        __syncthreads();

        f32x4 acc0 = {0.f, 0.f, 0.f, 0.f}, acc1 = {0.f, 0.f, 0.f, 0.f};
#pragma unroll
        for (int c = 0; c < 3; ++c) {
            bf16x8 a = *(const bf16x8*)&atile[lm * LSTR + c * 32 + quad * 8];
            acc0 = __builtin_amdgcn_mfma_f32_16x16x32_bf16(a, bfrag[0][c], acc0, 0, 0, 0);
            acc1 = __builtin_amdgcn_mfma_f32_16x16x32_bf16(a, bfrag[1][c], acc1, 0, 0, 0);
        }
        // epilogue in C layout: col=lane&15 (j fixed per lane/tile), row=quad*4+r
#pragma unroll
        for (int t = 0; t < 2; ++t) {
            const int j = t ? j1c : j0c;
            const float cbj = t ? cb1 : cb0;
            const float ehj = t ? eh1 : eh0;
#pragma unroll
            for (int r = 0; r < 4; ++r) {
                const int rl = quad * 4 + r;
                if (rl < rows) {
                    const int s = ssrc[rl];
                    float dh = bf2f(Dh[(long)s * DD + j]);
                    float bh = bf2f(Bh[(long)s * DD + j]);
                    float en = (t ? acc1[r] : acc0[r]) + cbj + dh + ehj;
                    float sg = 1.f / (1.f + __expf(-en));
                    nacc[t] += bh * sg;
                    dacc[t] += sg;
                    float old = bf2f(atile[rl * LSTR + j]);
                    ebuf[(long)(chunk + rl) * DD + j] = f2bf(old + fmaxf(en, 0.f));
                }
            }
        }
        __syncthreads();   // atile reused next chunk
    }
    // reduce num/den over quads (butterfly), stash per-col sums
#pragma unroll
    for (int t = 0; t < 2; ++t) {
        float x = nacc[t], y = dacc[t];
        x += __shfl_xor(x, 16); y += __shfl_xor(y, 16);
        x += __shfl_xor(x, 32); y += __shfl_xor(y, 32);
        if (lane < 16) { snum[(2 * wv + t) * 16 + lane] = x; sden[(2 * wv + t) * 16 + lane] = y; }
    }
    __syncthreads();
    if (tid < DD) {
        float val = Ah[(long)n * DD + tid] + snum[tid] / (sden[tid] + EPSF);
        hbuf[(long)n * DD + tid] += fmaxf(val, 0.f);
    }
#undef LSTR
}

// small MLP stage, one thread per output element
__global__ void k_mlp(const float* __restrict__ X, const float* __restrict__ W,
                      const float* __restrict__ B, float* __restrict__ Y,
                      int K, int Dout, int act, long total) {
    long idx = (long)blockIdx.x * blockDim.x + threadIdx.x;
    if (idx >= total) return;
    int row = (int)(idx / Dout);
    int j = (int)(idx - (long)row * Dout);
    const float* xr = X + (long)row * K;
    float acc = B[j];
    for (int k = 0; k < K; ++k) acc = fmaf(xr[k], W[k * Dout + j], acc);
    if (act == 1) acc = fmaxf(acc, 0.f);
    else if (act == 2) acc = 1.f / (1.f + __expf(-acc));
    Y[idx] = acc;
}

extern "C" void kernel_launch(void* const* d_in, const int* in_sizes, int n_in,
                              void* d_out, int out_size, void* d_ws, size_t ws_size,
                              hipStream_t stream) {
    const float* h_in = (const float*)d_in[0];
    const float* e_in = (const float*)d_in[1];
    const int* src = (const int*)d_in[2];
    const int* dst = (const int*)d_in[3];
    const float* fp_w = (const float*)d_in[4];
    const float* fp_b = (const float*)d_in[5];
    const float* ep_w = (const float*)d_in[6];
    const float* ep_b = (const float*)d_in[7];
    const float* A_w = (const float*)d_in[8];
    const float* A_b = (const float*)d_in[9];
    const float* B_w = (const float*)d_in[10];
    const float* B_b = (const float*)d_in[11];
    const float* C_w = (const float*)d_in[12];
    const float* C_b = (const float*)d_in[13];
    const float* D_w = (const float*)d_in[14];
    const float* D_b = (const float*)d_in[15];
    const float* E_w = (const float*)d_in[16];
    const float* E_b = (const float*)d_in[17];
    const float* mlp0_w = (const float*)d_in[18];
    const float* mlp0_b = (const float*)d_in[19];
    const float* mlp1_w = (const float*)d_in[20];
    const float* mlp1_b = (const float*)d_in[21];
    const float* mlp2_w = (const float*)d_in[22];
    const float* mlp2_b = (const float*)d_in[23];
    float* out = (float*)d_out;

    const size_t ND = (size_t)NN * DD;
    const size_t ED = (size_t)NE * DD;
    char* w = (char*)d_ws;
    float* hbuf = (float*)w; w += ND * 4;
    float* Ahb  = (float*)w; w += ND * 4;
    u16* Bhb = (u16*)w; w += ND * 2;
    u16* Dhb = (u16*)w; w += ND * 2;
    u16* Ehb = (u16*)w; w += ND * 2;
    u16* ebuf = (u16*)w; w += ED * 2;
    int* counts  = (int*)w; w += (size_t)NN * 4;
    int* row_ptr = (int*)w; w += (size_t)(NN + 1) * 4 + 12;
    int* cursor  = (int*)w; w += (size_t)NN * 4;
    int* eperm   = (int*)w; w += (size_t)NE * 4;
    int* srcp    = (int*)w; w += (size_t)NE * 4;
    u16* cwf     = (u16*)w; w += (size_t)NL * 6 * 3 * 64 * 8 * 2;   // 73.7 KB
    size_t need = (size_t)(w - (char*)d_ws);
    if (ws_size < need) return;  // uniform -> graph-safe; fails absmax as diagnostic

    // CSR build (dst-sorted edge permutation) + Cw fragment pack (all layers)
    k_zero_i<<<(NN + 255) / 256, 256, 0, stream>>>(counts, NN);
    k_hist<<<(NE + 255) / 256, 256, 0, stream>>>(dst, counts);
    k_scan<<<1, 1024, 0, stream>>>(counts, row_ptr, cursor, NN);
    k_scatter<<<(NE + 255) / 256, 256, 0, stream>>>(src, dst, cursor, eperm, srcp);
    k_packCw<<<(NL * 6 * 3 * 64 + 255) / 256, 256, 0, stream>>>(C_w, cwf);

    // input projections (edge proj lands in dst-sorted order), LDS-tiled
    k_proj_t<false, false><<<(NN + 31) / 32, 192, 0, stream>>>(h_in, fp_w, fp_b, hbuf, nullptr, NN);
    k_proj_t<true, true><<<NE / 32, 192, 0, stream>>>(e_in, ep_w, ep_b, ebuf, eperm, NE);

    const int gN = (NN + 31) / 32;
    for (int l = 0; l < NL; ++l) {
        const float* Aw = A_w + (size_t)l * DD * DD; const float* Ab = A_b + (size_t)l * DD;
        const float* Bw = B_w + (size_t)l * DD * DD; const float* Bb = B_b + (size_t)l * DD;
        const float* Cb = C_b + (size_t)l * DD;
        const float* Dw = D_w + (size_t)l * DD * DD; const float* Db = D_b + (size_t)l * DD;
        const float* Ew = E_w + (size_t)l * DD * DD; const float* Eb = E_b + (size_t)l * DD;
        const u16* cwf_l = cwf + (size_t)l * 6 * 3 * 64 * 8;

        k_gemm4<<<gN, 192, 0, stream>>>(hbuf, Aw, Ab, Bw, Bb, Dw, Db, Ew, Eb,
                                        Ahb, Bhb, Dhb, Ehb, NN);
        k_node_edge<<<NN, 192, 0, stream>>>(ebuf, cwf_l, Cb, Dhb, Ehb, Bhb, srcp, row_ptr,
                                            Ahb, hbuf);
    }

    // MLP readout: 96 -> 48 (relu) -> 24 (relu) -> 10 (sigmoid). Reuse Ahb as temps.
    float* y1 = Ahb;
    float* y2 = Ahb + (size_t)NN * 48;
    long t0 = (long)NN * 48, t1 = (long)NN * 24, t2 = (long)NN * NCLS;
    k_mlp<<<(int)((t0 + 255) / 256), 256, 0, stream>>>(hbuf, mlp0_w, mlp0_b, y1, DD, 48, 1, t0);
    k_mlp<<<(int)((t1 + 255) / 256), 256, 0, stream>>>(y1, mlp1_w, mlp1_b, y2, 48, 24, 1, t1);
    k_mlp<<<(int)((t2 + 255) / 256), 256, 0, stream>>>(y2, mlp2_w, mlp2_b, out, 24, NCLS, 2, t2);
}

// Round 9
// 1919.371 us; speedup vs baseline: 2.2078x; 1.0539x over previous
//
#include <hip/hip_runtime.h>

#define NN 50000
#define NE 800000
#define DIN 32
#define DD 96
#define NL 4
#define NCLS 10
#define EPSF 1e-6f

typedef unsigned short u16;
typedef unsigned int u32;

typedef __bf16 bf16x8 __attribute__((ext_vector_type(8)));
typedef float f32x4 __attribute__((ext_vector_type(4)));

static __device__ __forceinline__ float bf2f(u16 u) {
    return __uint_as_float(((u32)u) << 16);
}
static __device__ __forceinline__ u16 f2bf(float f) {
    u32 x = __float_as_uint(f);
    x += 0x7FFFu + ((x >> 16) & 1u);   // round-to-nearest-even
    return (u16)(x >> 16);
}
static __device__ __forceinline__ u32 pk2(float a, float b) {
    return (u32)f2bf(a) | ((u32)f2bf(b) << 16);
}
static __device__ __forceinline__ float unlo(u32 u) { return __uint_as_float(u << 16); }
static __device__ __forceinline__ float unhi(u32 u) { return __uint_as_float(u & 0xFFFF0000u); }

__global__ void k_zero_i(int* __restrict__ p, int n) {
    int i = blockIdx.x * blockDim.x + threadIdx.x;
    if (i < n) p[i] = 0;
}

__global__ void k_hist(const int* __restrict__ dst, int* __restrict__ counts) {
    int i = blockIdx.x * blockDim.x + threadIdx.x;
    if (i < NE) atomicAdd(&counts[dst[i]], 1);
}

// single-block exclusive scan over n counts -> row_ptr[0..n], cursor copy.
__global__ __launch_bounds__(1024) void k_scan(const int* __restrict__ counts,
                                               int* __restrict__ row_ptr,
                                               int* __restrict__ cursor, int n) {
    __shared__ int wsum[16];
    __shared__ int carry_s;
    const int tid = threadIdx.x;
    const int lane = tid & 63, wid = tid >> 6;
    if (tid == 0) carry_s = 0;
    __syncthreads();
    for (int base = 0; base < n; base += 1024) {
        int i = base + tid;
        int v = (i < n) ? counts[i] : 0;
        int x = v;
#pragma unroll
        for (int off = 1; off < 64; off <<= 1) {
            int t = __shfl_up(x, (unsigned)off, 64);
            if (lane >= off) x += t;
        }
        if (lane == 63) wsum[wid] = x;
        __syncthreads();
        if (wid == 0 && lane < 16) {
            int s = wsum[lane];
#pragma unroll
            for (int off = 1; off < 16; off <<= 1) {
                int t = __shfl_up(s, (unsigned)off, 16);
                if (lane >= off) s += t;
            }
            wsum[lane] = s;
        }
        __syncthreads();
        int wbase = (wid > 0) ? wsum[wid - 1] : 0;
        int carry = carry_s;
        int excl = carry + wbase + x - v;
        if (i < n) { row_ptr[i] = excl; cursor[i] = excl; }
        __syncthreads();
        if (tid == 0) carry_s = carry + wsum[15];
        __syncthreads();
    }
    if (tid == 0) row_ptr[n] = carry_s;
}

__global__ void k_scatter(const int* __restrict__ src, const int* __restrict__ dst,
                          int* __restrict__ cursor, int* __restrict__ eperm,
                          int* __restrict__ srcp) {
    int i = blockIdx.x * blockDim.x + threadIdx.x;
    if (i >= NE) return;
    int pos = atomicAdd(&cursor[dst[i]], 1);
    eperm[pos] = i;
    srcp[pos] = src[i];
}

// Pack all 4 layers' Cw into MFMA B-fragment order (bf16):
// cwf[l][tile][c][lane][j] = bf16(Cw[l][k=c*32+(lane>>4)*8+j][n=tile*16+(lane&15)])
__global__ void k_packCw(const float* __restrict__ Cw_all, u16* __restrict__ cwf) {
    int q = blockIdx.x * blockDim.x + threadIdx.x;   // fragment index
    if (q >= NL * 6 * 3 * 64) return;
    int l = q / (6 * 3 * 64);
    int rem = q - l * (6 * 3 * 64);
    int tile = rem / (3 * 64);
    int rem2 = rem - tile * (3 * 64);
    int c = rem2 >> 6, lane = rem2 & 63;
    const float* Cw = Cw_all + (long)l * DD * DD;
    int n = tile * 16 + (lane & 15);
    int k0 = c * 32 + (lane >> 4) * 8;
    u16 w[8];
#pragma unroll
    for (int j = 0; j < 8; ++j) w[j] = f2bf(Cw[(k0 + j) * DD + n]);
    *(uint4*)&cwf[(long)q * 8] = *(uint4*)w;
}

// Persistent double-buffered input projection:
// Y[row,:] = X[permrow,:DIN] @ W[DIN,DD] + B. W staged once/block; grid-stride
// over 32-row tiles; next tile's gather prefetched into regs during compute.
template <bool BFOUT, bool PERM>
__global__ __launch_bounds__(192) void k_proj_p(const float* __restrict__ X,
                                                const float* __restrict__ W,
                                                const float* __restrict__ B,
                                                void* __restrict__ Y,
                                                const int* __restrict__ eperm,
                                                int nrows, int ntiles) {
    __shared__ float ws_w[DIN * DD];       // 12 KB [k][j]
    __shared__ float xs[2][32][DIN + 1];   // 8.4 KB double-buffered x tiles
    const int tid = threadIdx.x;
    {
        const float4* Wv = (const float4*)W;
        float4* wv = (float4*)ws_w;
#pragma unroll
        for (int t = 0; t < 4; ++t) wv[tid + t * 192] = Wv[tid + t * 192];
    }
    const int je = tid % 24, ge = tid / 24;
    const int j0 = je * 4, r0 = ge * 4;
    const float b0 = B[j0], b1 = B[j0 + 1], b2 = B[j0 + 2], b3 = B[j0 + 3];
    // gather mapping: q in [0,256): r=q>>3, c4=q&7 ; q0=tid, q1=tid+192 (tid<64)
    const int r_a = tid >> 3, c_a = tid & 7;
    const int r_b = (tid + 192) >> 3, c_b = (tid + 192) & 7;

    int cur = blockIdx.x;
    if (cur >= ntiles) return;
    // initial load of tile `cur` into xs[0]
    {
        int row0 = cur * 32;
        float4 v = make_float4(0.f, 0.f, 0.f, 0.f);
        int grow = row0 + r_a;
        if (grow < nrows) {
            long srow = PERM ? (long)eperm[grow] : (long)grow;
            v = *(const float4*)&X[srow * DIN + c_a * 4];
        }
        *(float4*)&xs[0][r_a][c_a * 4] = v;
        if (tid < 64) {
            float4 u = make_float4(0.f, 0.f, 0.f, 0.f);
            int gr2 = row0 + r_b;
            if (gr2 < nrows) {
                long srow = PERM ? (long)eperm[gr2] : (long)gr2;
                u = *(const float4*)&X[srow * DIN + c_b * 4];
            }
            *(float4*)&xs[0][r_b][c_b * 4] = u;
        }
    }
    __syncthreads();

    int buf = 0;
    while (cur < ntiles) {
        const int nxt = cur + gridDim.x;
        // prefetch next tile's gather into registers (covered by compute below)
        float4 n0 = make_float4(0.f, 0.f, 0.f, 0.f);
        float4 n1 = make_float4(0.f, 0.f, 0.f, 0.f);
        if (nxt < ntiles) {
            int row0n = nxt * 32;
            int grow = row0n + r_a;
            if (grow < nrows) {
                long srow = PERM ? (long)eperm[grow] : (long)grow;
                n0 = *(const float4*)&X[srow * DIN + c_a * 4];
            }
            if (tid < 64) {
                int gr2 = row0n + r_b;
                if (gr2 < nrows) {
                    long srow = PERM ? (long)eperm[gr2] : (long)gr2;
                    n1 = *(const float4*)&X[srow * DIN + c_b * 4];
                }
            }
        }
        // compute current tile from xs[buf]
        float acc[4][4] = {};
#pragma unroll
        for (int kk = 0; kk < DIN; kk += 4) {
            float4 w0 = *(const float4*)&ws_w[(kk + 0) * DD + j0];
            float4 w1 = *(const float4*)&ws_w[(kk + 1) * DD + j0];
            float4 w2 = *(const float4*)&ws_w[(kk + 2) * DD + j0];
            float4 w3 = *(const float4*)&ws_w[(kk + 3) * DD + j0];
#pragma unroll
            for (int i = 0; i < 4; ++i) {
                const float a0 = xs[buf][r0 + i][kk + 0], a1 = xs[buf][r0 + i][kk + 1];
                const float a2 = xs[buf][r0 + i][kk + 2], a3 = xs[buf][r0 + i][kk + 3];
                acc[i][0] = fmaf(a0, w0.x, fmaf(a1, w1.x, fmaf(a2, w2.x, fmaf(a3, w3.x, acc[i][0]))));
                acc[i][1] = fmaf(a0, w0.y, fmaf(a1, w1.y, fmaf(a2, w2.y, fmaf(a3, w3.y, acc[i][1]))));
                acc[i][2] = fmaf(a0, w0.z, fmaf(a1, w1.z, fmaf(a2, w2.z, fmaf(a3, w3.z, acc[i][2]))));
                acc[i][3] = fmaf(a0, w0.w, fmaf(a1, w1.w, fmaf(a2, w2.w, fmaf(a3, w3.w, acc[i][3]))));
            }
        }
        {
            const int row0 = cur * 32;
#pragma unroll
            for (int i = 0; i < 4; ++i) {
                int row = row0 + r0 + i;
                if (row >= nrows) continue;
                float v0 = acc[i][0] + b0, v1 = acc[i][1] + b1;
                float v2 = acc[i][2] + b2, v3 = acc[i][3] + b3;
                if (BFOUT) {
                    *(uint2*)((u16*)Y + (long)row * DD + j0) = make_uint2(pk2(v0, v1), pk2(v2, v3));
                } else {
                    *(float4*)((float*)Y + (long)row * DD + j0) = make_float4(v0, v1, v2, v3);
                }
            }
        }
        // publish prefetched tile into the other buffer
        if (nxt < ntiles) {
            *(float4*)&xs[buf ^ 1][r_a][c_a * 4] = n0;
            if (tid < 64) *(float4*)&xs[buf ^ 1][r_b][c_b * 4] = n1;
        }
        __syncthreads();
        cur = nxt;
        buf ^= 1;
    }
}

// Fused 4-way node GEMM (VALU path).
__global__ __launch_bounds__(192) void k_gemm4(const float* __restrict__ X,
                                               const float* __restrict__ W0, const float* __restrict__ b0,
                                               const float* __restrict__ W1, const float* __restrict__ b1,
                                               const float* __restrict__ W2, const float* __restrict__ b2,
                                               const float* __restrict__ W3, const float* __restrict__ b3,
                                               float* __restrict__ Y0, u16* __restrict__ Y1,
                                               u16* __restrict__ Y2, u16* __restrict__ Y3,
                                               int nrows) {
    __shared__ u32 wsp[DD * 48];
    __shared__ float xs[32 * 100];
    const int tid = threadIdx.x;
    const int row0 = blockIdx.x * 32;
#pragma unroll
    for (int t = 0; t < 4; ++t) {
        int q = tid + t * 192;
        int r = q / 24, c4 = q - r * 24;
        int row = row0 + r;
        float4 v = make_float4(0.f, 0.f, 0.f, 0.f);
        if (row < nrows) v = *(const float4*)&X[(long)row * DD + c4 * 4];
        *(float4*)&xs[r * 100 + c4 * 4] = v;
    }
    const float* Ws[4] = {W0, W1, W2, W3};
    const float* Bs[4] = {b0, b1, b2, b3};
    const int je = tid % 24, ge = tid / 24;
    const int j0 = je * 4, r0 = ge * 4;
    for (int m = 0; m < 4; ++m) {
        {
            const float4* Wv = (const float4*)Ws[m];
            uint2* wv = (uint2*)wsp;
#pragma unroll
            for (int t = 0; t < 12; ++t) {
                float4 v = Wv[tid + t * 192];
                wv[tid + t * 192] = make_uint2(pk2(v.x, v.y), pk2(v.z, v.w));
            }
        }
        __syncthreads();
        float acc[4][4] = {};
#pragma unroll 4
        for (int k4 = 0; k4 < 24; ++k4) {
            const int kk = k4 * 4;
            float4 a0 = *(const float4*)&xs[(r0 + 0) * 100 + kk];
            float4 a1 = *(const float4*)&xs[(r0 + 1) * 100 + kk];
            float4 a2 = *(const float4*)&xs[(r0 + 2) * 100 + kk];
            float4 a3 = *(const float4*)&xs[(r0 + 3) * 100 + kk];
            uint2 u0 = *(const uint2*)&wsp[(kk + 0) * 48 + je * 2];
            uint2 u1 = *(const uint2*)&wsp[(kk + 1) * 48 + je * 2];
            uint2 u2 = *(const uint2*)&wsp[(kk + 2) * 48 + je * 2];
            uint2 u3 = *(const uint2*)&wsp[(kk + 3) * 48 + je * 2];
            float4 w0 = make_float4(unlo(u0.x), unhi(u0.x), unlo(u0.y), unhi(u0.y));
            float4 w1 = make_float4(unlo(u1.x), unhi(u1.x), unlo(u1.y), unhi(u1.y));
            float4 w2 = make_float4(unlo(u2.x), unhi(u2.x), unlo(u2.y), unhi(u2.y));
            float4 w3 = make_float4(unlo(u3.x), unhi(u3.x), unlo(u3.y), unhi(u3.y));
#define ROWFMA(i, a)                                                                  \
    acc[i][0] = fmaf(a.x, w0.x, fmaf(a.y, w1.x, fmaf(a.z, w2.x, fmaf(a.w, w3.x, acc[i][0])))); \
    acc[i][1] = fmaf(a.x, w0.y, fmaf(a.y, w1.y, fmaf(a.z, w2.y, fmaf(a.w, w3.y, acc[i][1])))); \
    acc[i][2] = fmaf(a.x, w0.z, fmaf(a.y, w1.z, fmaf(a.z, w2.z, fmaf(a.w, w3.z, acc[i][2])))); \
    acc[i][3] = fmaf(a.x, w0.w, fmaf(a.y, w1.w, fmaf(a.z, w2.w, fmaf(a.w, w3.w, acc[i][3]))));
            ROWFMA(0, a0) ROWFMA(1, a1) ROWFMA(2, a2) ROWFMA(3, a3)
#undef ROWFMA
        }
        const float* Bm = Bs[m];
        const float bb0 = Bm[j0], bb1 = Bm[j0 + 1], bb2 = Bm[j0 + 2], bb3 = Bm[j0 + 3];
#pragma unroll
        for (int i = 0; i < 4; ++i) {
            int row = row0 + r0 + i;
            if (row >= nrows) continue;
            float v0 = acc[i][0] + bb0, v1 = acc[i][1] + bb1;
            float v2 = acc[i][2] + bb2, v3 = acc[i][3] + bb3;
            if (m == 0) {
                *(float4*)&Y0[(long)row * DD + j0] = make_float4(v0, v1, v2, v3);
            } else {
                u16* Yp = (m == 1) ? Y1 : ((m == 2) ? Y2 : Y3);
                *(uint2*)&Yp[(long)row * DD + j0] = make_uint2(pk2(v0, v1), pk2(v2, v3));
            }
        }
        __syncthreads();
    }
}

// Per-destination-node fused edge+aggregate kernel — MFMA with register-resident
// B-fragments (pre-packed Cw). LDS only for the 16-edge A-tile + reductions.
__global__ __launch_bounds__(192) void k_node_edge(u16* ebuf,
                                                   const u16* __restrict__ cwf,  // [6][3][64][8]
                                                   const float* __restrict__ Cb,
                                                   const u16* __restrict__ Dh,
                                                   const u16* __restrict__ Eh,
                                                   const u16* __restrict__ Bh,
                                                   const int* __restrict__ srcp,
                                                   const int* __restrict__ row_ptr,
                                                   const float* __restrict__ Ah,
                                                   float* __restrict__ hbuf) {
#define LSTR 104
    __shared__ u16 atile[16 * LSTR];  // 3.3 KB  e-tile bf16 [m][k]
    __shared__ float snum[DD], sden[DD];
    __shared__ int ssrc[16];
    const int tid = threadIdx.x;
    const int n = blockIdx.x;
    const int r0 = row_ptr[n], r1 = row_ptr[n + 1];
    const int lane = tid & 63;
    const int wv = tid >> 6;          // wave 0..2 -> col tiles {2wv, 2wv+1}
    const int lm = lane & 15;
    const int quad = lane >> 4;
    const int srow = tid / 12, sc8 = tid - srow * 12;

    // B-fragments: 2 tiles x 3 K-steps, register-resident for the whole block
    bf16x8 bfrag[2][3];
#pragma unroll
    for (int t = 0; t < 2; ++t)
#pragma unroll
        for (int c = 0; c < 3; ++c)
            bfrag[t][c] = *(const bf16x8*)&cwf[(((long)(2 * wv + t) * 3 + c) * 64 + lane) * 8];

    // per-lane column constants: j = (2wv+t)*16 + lm
    const int j0c = (2 * wv + 0) * 16 + lm;
    const int j1c = (2 * wv + 1) * 16 + lm;
    const float cb0 = Cb[j0c], cb1 = Cb[j1c];
    const float eh0 = bf2f(Eh[(long)n * DD + j0c]);
    const float eh1 = bf2f(Eh[(long)n * DD + j1c]);
    float nacc[2] = {0.f, 0.f}, dacc[2] = {0.f, 0.f};

    for (int chunk = r0; chunk < r1; chunk += 16) {
        const int rows = min(16, r1 - chunk);
        if (srow < rows) {   // pad rows left stale: their C rows are never read
            uint4 u = *(const uint4*)&ebuf[(long)(chunk + srow) * DD + sc8 * 8];
            *(uint4*)&atile[srow * LSTR + sc8 * 8] = u;
        }
        if (tid < 16) ssrc[tid] = (chunk + tid < r1) ? srcp[chunk + tid] : 0;
        __syncthreads();

        f32x4 acc0 = {0.f, 0.f, 0.f, 0.f}, acc1 = {0.f, 0.f, 0.f, 0.f};
#pragma unroll
        for (int c = 0; c < 3; ++c) {
            bf16x8 a = *(const bf16x8*)&atile[lm * LSTR + c * 32 + quad * 8];
            acc0 = __builtin_amdgcn_mfma_f32_16x16x32_bf16(a, bfrag[0][c], acc0, 0, 0, 0);
            acc1 = __builtin_amdgcn_mfma_f32_16x16x32_bf16(a, bfrag[1][c], acc1, 0, 0, 0);
        }
        // epilogue in C layout: col=lane&15 (j fixed per lane/tile), row=quad*4+r
#pragma unroll
        for (int t = 0; t < 2; ++t) {
            const int j = t ? j1c : j0c;
            const float cbj = t ? cb1 : cb0;
            const float ehj = t ? eh1 : eh0;
#pragma unroll
            for (int r = 0; r < 4; ++r) {
                const int rl = quad * 4 + r;
                if (rl < rows) {
                    const int s = ssrc[rl];
                    float dh = bf2f(Dh[(long)s * DD + j]);
                    float bh = bf2f(Bh[(long)s * DD + j]);
                    float en = (t ? acc1[r] : acc0[r]) + cbj + dh + ehj;
                    float sg = 1.f / (1.f + __expf(-en));
                    nacc[t] += bh * sg;
                    dacc[t] += sg;
                    float old = bf2f(atile[rl * LSTR + j]);
                    ebuf[(long)(chunk + rl) * DD + j] = f2bf(old + fmaxf(en, 0.f));
                }
            }
        }
        __syncthreads();   // atile reused next chunk
    }
    // reduce num/den over quads (butterfly), stash per-col sums
#pragma unroll
    for (int t = 0; t < 2; ++t) {
        float x = nacc[t], y = dacc[t];
        x += __shfl_xor(x, 16); y += __shfl_xor(y, 16);
        x += __shfl_xor(x, 32); y += __shfl_xor(y, 32);
        if (lane < 16) { snum[(2 * wv + t) * 16 + lane] = x; sden[(2 * wv + t) * 16 + lane] = y; }
    }
    __syncthreads();
    if (tid < DD) {
        float val = Ah[(long)n * DD + tid] + snum[tid] / (sden[tid] + EPSF);
        hbuf[(long)n * DD + tid] += fmaxf(val, 0.f);
    }
#undef LSTR
}

// small MLP stage, one thread per output element
__global__ void k_mlp(const float* __restrict__ X, const float* __restrict__ W,
                      const float* __restrict__ B, float* __restrict__ Y,
                      int K, int Dout, int act, long total) {
    long idx = (long)blockIdx.x * blockDim.x + threadIdx.x;
    if (idx >= total) return;
    int row = (int)(idx / Dout);
    int j = (int)(idx - (long)row * Dout);
    const float* xr = X + (long)row * K;
    float acc = B[j];
    for (int k = 0; k < K; ++k) acc = fmaf(xr[k], W[k * Dout + j], acc);
    if (act == 1) acc = fmaxf(acc, 0.f);
    else if (act == 2) acc = 1.f / (1.f + __expf(-acc));
    Y[idx] = acc;
}

extern "C" void kernel_launch(void* const* d_in, const int* in_sizes, int n_in,
                              void* d_out, int out_size, void* d_ws, size_t ws_size,
                              hipStream_t stream) {
    const float* h_in = (const float*)d_in[0];
    const float* e_in = (const float*)d_in[1];
    const int* src = (const int*)d_in[2];
    const int* dst = (const int*)d_in[3];
    const float* fp_w = (const float*)d_in[4];
    const float* fp_b = (const float*)d_in[5];
    const float* ep_w = (const float*)d_in[6];
    const float* ep_b = (const float*)d_in[7];
    const float* A_w = (const float*)d_in[8];
    const float* A_b = (const float*)d_in[9];
    const float* B_w = (const float*)d_in[10];
    const float* B_b = (const float*)d_in[11];
    const float* C_w = (const float*)d_in[12];
    const float* C_b = (const float*)d_in[13];
    const float* D_w = (const float*)d_in[14];
    const float* D_b = (const float*)d_in[15];
    const float* E_w = (const float*)d_in[16];
    const float* E_b = (const float*)d_in[17];
    const float* mlp0_w = (const float*)d_in[18];
    const float* mlp0_b = (const float*)d_in[19];
    const float* mlp1_w = (const float*)d_in[20];
    const float* mlp1_b = (const float*)d_in[21];
    const float* mlp2_w = (const float*)d_in[22];
    const float* mlp2_b = (const float*)d_in[23];
    float* out = (float*)d_out;

    const size_t ND = (size_t)NN * DD;
    const size_t ED = (size_t)NE * DD;
    char* w = (char*)d_ws;
    float* hbuf = (float*)w; w += ND * 4;
    float* Ahb  = (float*)w; w += ND * 4;
    u16* Bhb = (u16*)w; w += ND * 2;
    u16* Dhb = (u16*)w; w += ND * 2;
    u16* Ehb = (u16*)w; w += ND * 2;
    u16* ebuf = (u16*)w; w += ED * 2;
    int* counts  = (int*)w; w += (size_t)NN * 4;
    int* row_ptr = (int*)w; w += (size_t)(NN + 1) * 4 + 12;
    int* cursor  = (int*)w; w += (size_t)NN * 4;
    int* eperm   = (int*)w; w += (size_t)NE * 4;
    int* srcp    = (int*)w; w += (size_t)NE * 4;
    u16* cwf     = (u16*)w; w += (size_t)NL * 6 * 3 * 64 * 8 * 2;   // 73.7 KB
    size_t need = (size_t)(w - (char*)d_ws);
    if (ws_size < need) return;  // uniform -> graph-safe; fails absmax as diagnostic

    // CSR build (dst-sorted edge permutation) + Cw fragment pack (all layers)
    k_zero_i<<<(NN + 255) / 256, 256, 0, stream>>>(counts, NN);
    k_hist<<<(NE + 255) / 256, 256, 0, stream>>>(dst, counts);
    k_scan<<<1, 1024, 0, stream>>>(counts, row_ptr, cursor, NN);
    k_scatter<<<(NE + 255) / 256, 256, 0, stream>>>(src, dst, cursor, eperm, srcp);
    k_packCw<<<(NL * 6 * 3 * 64 + 255) / 256, 256, 0, stream>>>(C_w, cwf);

    // input projections (edge proj lands in dst-sorted order), persistent+dbuf
    {
        const int ntH = (NN + 31) / 32;               // 1563
        const int ntE = NE / 32;                      // 25000
        const int gH = ntH < 1280 ? ntH : 1280;
        const int gE = 1280;
        k_proj_p<false, false><<<gH, 192, 0, stream>>>(h_in, fp_w, fp_b, hbuf, nullptr, NN, ntH);
        k_proj_p<true, true><<<gE, 192, 0, stream>>>(e_in, ep_w, ep_b, ebuf, eperm, NE, ntE);
    }

    const int gN = (NN + 31) / 32;
    for (int l = 0; l < NL; ++l) {
        const float* Aw = A_w + (size_t)l * DD * DD; const float* Ab = A_b + (size_t)l * DD;
        const float* Bw = B_w + (size_t)l * DD * DD; const float* Bb = B_b + (size_t)l * DD;
        const float* Cb = C_b + (size_t)l * DD;
        const float* Dw = D_w + (size_t)l * DD * DD; const float* Db = D_b + (size_t)l * DD;
        const float* Ew = E_w + (size_t)l * DD * DD; const float* Eb = E_b + (size_t)l * DD;
        const u16* cwf_l = cwf + (size_t)l * 6 * 3 * 64 * 8;

        k_gemm4<<<gN, 192, 0, stream>>>(hbuf, Aw, Ab, Bw, Bb, Dw, Db, Ew, Eb,
                                        Ahb, Bhb, Dhb, Ehb, NN);
        k_node_edge<<<NN, 192, 0, stream>>>(ebuf, cwf_l, Cb, Dhb, Ehb, Bhb, srcp, row_ptr,
                                            Ahb, hbuf);
    }

    // MLP readout: 96 -> 48 (relu) -> 24 (relu) -> 10 (sigmoid). Reuse Ahb as temps.
    float* y1 = Ahb;
    float* y2 = Ahb + (size_t)NN * 48;
    long t0 = (long)NN * 48, t1 = (long)NN * 24, t2 = (long)NN * NCLS;
    k_mlp<<<(int)((t0 + 255) / 256), 256, 0, stream>>>(hbuf, mlp0_w, mlp0_b, y1, DD, 48, 1, t0);
    k_mlp<<<(int)((t1 + 255) / 256), 256, 0, stream>>>(y1, mlp1_w, mlp1_b, y2, 48, 24, 1, t1);
    k_mlp<<<(int)((t2 + 255) / 256), 256, 0, stream>>>(y2, mlp2_w, mlp2_b, out, 24, NCLS, 2, t2);
}